// Round 3
// baseline (1759.326 us; speedup 1.0000x reference)
//
#include <hip/hip_runtime.h>
#include <hip/hip_bf16.h>
#include <math.h>

#define N 4096
#define IN_FT 512
#define OUT_FT 512
#define COS_THR 0.5f
#define COS_K 10
#define EPSN 1e-12f
#define CAP 256          // max stored nnz per row/col (actual ~10)
#define NW (N / 32)      // bitmask words per row

#define BM 64
#define BN 64
#define BK 16

// ---------- row-normalize x ----------
__global__ __launch_bounds__(256) void rownorm_k(const float* __restrict__ x,
                                                 float* __restrict__ xn) {
    int row = blockIdx.x;
    const float* xr = x + (size_t)row * IN_FT;
    float s = 0.f;
    for (int j = threadIdx.x; j < IN_FT; j += 256) { float v = xr[j]; s += v * v; }
    __shared__ float red[256];
    red[threadIdx.x] = s; __syncthreads();
    for (int off = 128; off > 0; off >>= 1) {
        if (threadIdx.x < off) red[threadIdx.x] += red[threadIdx.x + off];
        __syncthreads();
    }
    float inv = 1.0f / fmaxf(sqrtf(red[0]), 1e-12f);
    for (int j = threadIdx.x; j < IN_FT; j += 256)
        xn[(size_t)row * IN_FT + j] = xr[j] * inv;
}

// ---------- C[M,N] = A[M,K] @ B[N,K]^T (+bias), f32 ----------
// (byte-identical cos path to the round-0 passing kernel: top-k selection
//  depends on its exact rounding)
__global__ __launch_bounds__(256) void matmul_abt_k(const float* __restrict__ A,
                                                    const float* __restrict__ B,
                                                    const float* __restrict__ bias,
                                                    float* __restrict__ C,
                                                    int K, int lda, int ldb, int ldc) {
    __shared__ float As[BK][BM + 1];
    __shared__ float Bs[BK][BN + 1];
    int i0 = blockIdx.y * BM, j0 = blockIdx.x * BN;
    int tid = threadIdx.x;
    int tx = tid & 15, ty = tid >> 4;
    float acc[4][4] = {{0.f}};
    for (int k0 = 0; k0 < K; k0 += BK) {
#pragma unroll
        for (int l = 0; l < 4; ++l) {
            int idx = tid + l * 256;
            int m = idx >> 4, k = idx & 15;
            As[k][m] = A[(size_t)(i0 + m) * lda + k0 + k];
        }
#pragma unroll
        for (int l = 0; l < 4; ++l) {
            int idx = tid + l * 256;
            int n = idx >> 4, k = idx & 15;
            Bs[k][n] = B[(size_t)(j0 + n) * ldb + k0 + k];
        }
        __syncthreads();
#pragma unroll
        for (int k = 0; k < BK; ++k) {
            float a[4], b[4];
#pragma unroll
            for (int i = 0; i < 4; ++i) a[i] = As[k][ty * 4 + i];
#pragma unroll
            for (int j = 0; j < 4; ++j) b[j] = Bs[k][tx * 4 + j];
#pragma unroll
            for (int i = 0; i < 4; ++i)
#pragma unroll
                for (int j = 0; j < 4; ++j) acc[i][j] += a[i] * b[j];
        }
        __syncthreads();
    }
#pragma unroll
    for (int i = 0; i < 4; ++i) {
        int r = i0 + ty * 4 + i;
#pragma unroll
        for (int j = 0; j < 4; ++j) {
            int c = j0 + tx * 4 + j;
            float v = acc[i][j];
            if (bias) v += bias[c];
            C[(size_t)r * ldc + c] = v;
        }
    }
}

// ---------- per-row top-k + threshold -> bitmask ----------
__global__ __launch_bounds__(256) void topk_mask_k(const float* __restrict__ cosm,
                                                   unsigned* __restrict__ maskw) {
    int row = blockIdx.x;
    __shared__ float vals[N];
    __shared__ unsigned char flag[N];
    __shared__ float rv[256];
    __shared__ int ri[256];
    const float* crow = cosm + (size_t)row * N;
    for (int j = threadIdx.x; j < N; j += 256) {
        float v = crow[j];
        vals[j] = v;
        flag[j] = (v > COS_THR) ? 1 : 0;
    }
    __syncthreads();
    for (int t = 0; t < COS_K; ++t) {
        float best = -INFINITY;
        int bidx = 0x7fffffff;
        for (int j = threadIdx.x; j < N; j += 256) {
            float v = vals[j];
            if (v > best) { best = v; bidx = j; }  // ascending j -> lowest idx on tie
        }
        rv[threadIdx.x] = best; ri[threadIdx.x] = bidx;
        __syncthreads();
        for (int off = 128; off > 0; off >>= 1) {
            if (threadIdx.x < off) {
                float v2 = rv[threadIdx.x + off]; int i2 = ri[threadIdx.x + off];
                float v1 = rv[threadIdx.x];       int i1 = ri[threadIdx.x];
                if (v2 > v1 || (v2 == v1 && i2 < i1)) { rv[threadIdx.x] = v2; ri[threadIdx.x] = i2; }
            }
            __syncthreads();
        }
        int w = ri[0];
        if (threadIdx.x == 0) { vals[w] = -INFINITY; flag[w] = 1; }
        __syncthreads();
    }
    for (int wdx = threadIdx.x; wdx < NW; wdx += 256) {
        unsigned bits = 0;
#pragma unroll
        for (int b = 0; b < 32; ++b) bits |= (flag[wdx * 32 + b] ? 1u : 0u) << b;
        maskw[(size_t)row * NW + wdx] = bits;
    }
}

// ---------- hyperedge (column) lists: deterministic v-ascending scan ----------
__global__ __launch_bounds__(256) void build_cols_k(const unsigned* __restrict__ maskw,
                                                    const float* __restrict__ w1,
                                                    const float* __restrict__ Hmat,
                                                    int* __restrict__ elist,
                                                    float* __restrict__ eval_,
                                                    int* __restrict__ ecnt,
                                                    float* __restrict__ csum) {
    int e = blockIdx.x * 256 + threadIdx.x;
    int word = e >> 5;
    unsigned bit = 1u << (e & 31);
    int cnt = 0; float s = 0.f;
    for (int v = 0; v < N; ++v) {
        unsigned wv = maskw[(size_t)v * NW + word];
        if (wv & bit) {
            float val = w1[(size_t)v * N + e] * Hmat[(size_t)v * N + e];
            if (cnt < CAP) {
                elist[(size_t)e * CAP + cnt] = v;
                eval_[(size_t)e * CAP + cnt] = val;
            }
            s += fabsf(val);
            ++cnt;
        }
    }
    ecnt[e] = cnt < CAP ? cnt : CAP;
    csum[e] = s;
}

// ---------- node (row) lists: deterministic e-ascending scan ----------
__global__ __launch_bounds__(256) void build_rows_k(const unsigned* __restrict__ maskw,
                                                    const float* __restrict__ w2,
                                                    const float* __restrict__ Hmat,
                                                    int* __restrict__ rlist,
                                                    float* __restrict__ rval,
                                                    int* __restrict__ rcnt,
                                                    float* __restrict__ rsum) {
    int v = blockIdx.x * 256 + threadIdx.x;
    const unsigned* mrow = maskw + (size_t)v * NW;
    int cnt = 0; float s = 0.f;
    for (int w = 0; w < NW; ++w) {
        unsigned bits = mrow[w];
        while (bits) {
            int b = __builtin_ctz(bits);
            bits &= bits - 1;
            int e = w * 32 + b;
            float val = w2[(size_t)v * N + e] * Hmat[(size_t)v * N + e];
            if (cnt < CAP) {
                rlist[(size_t)v * CAP + cnt] = e;
                rval[(size_t)v * CAP + cnt] = val;
            }
            s += fabsf(val);
            ++cnt;
        }
    }
    rcnt[v] = cnt < CAP ? cnt : CAP;
    rsum[v] = s;
}

// ---------- dst[i,:] = (1/max(sum[i],eps)) * sum_j val[i,j] * src[list[i,j],:] ----------
__global__ __launch_bounds__(256) void spmm_k(const int* __restrict__ list,
                                              const float* __restrict__ val,
                                              const int* __restrict__ cnt,
                                              const float* __restrict__ sums,
                                              const float* __restrict__ src,
                                              float* __restrict__ dst) {
    int i = blockIdx.x;
    int f = threadIdx.x;
    int c = cnt[i];
    float acc0 = 0.f, acc1 = 0.f;
    for (int t = 0; t < c; ++t) {
        int j = list[(size_t)i * CAP + t];
        float a = val[(size_t)i * CAP + t];
        acc0 += a * src[(size_t)j * OUT_FT + f];
        acc1 += a * src[(size_t)j * OUT_FT + f + 256];
    }
    float sc = 1.0f / fmaxf(sums[i], EPSN);
    dst[(size_t)i * OUT_FT + f] = acc0 * sc;
    dst[(size_t)i * OUT_FT + f + 256] = acc1 * sc;
}

extern "C" void kernel_launch(void* const* d_in, const int* in_sizes, int n_in,
                              void* d_out, int out_size, void* d_ws, size_t ws_size,
                              hipStream_t stream) {
    const float* x      = (const float*)d_in[0];   // [4096,512]
    const float* Hmat   = (const float*)d_in[1];   // [4096,4096]
    const float* proj_w = (const float*)d_in[2];   // [512,512]
    const float* proj_b = (const float*)d_in[3];   // [512]
    const float* w1     = (const float*)d_in[4];   // [4096,4096]
    const float* w2     = (const float*)d_in[5];   // [4096,4096]
    float* out = (float*)d_out;

    char* ws = (char*)d_ws;
    // Layout. Tail buffers each 4096*4 = 16384 B, stride 16384 (round-2 bug:
    // was 16000 -> overlap -> garbage counts -> OOB gather -> GPU abort).
    float*    xn    = (float*)(ws + 0);           //  8 MB
    float*    cosm  = (float*)(ws + 8388608);     // 64 MB [8MB..72MB), dead after topk
    int*      elist = (int*)  (ws + 8388608);     //  4 MB (aliases dead cos)
    float*    eval_ = (float*)(ws + 12582912);    //  4 MB (aliases dead cos)
    int*      rlist = (int*)  (ws + 16777216);    //  4 MB (aliases dead cos)
    float*    rval  = (float*)(ws + 20971520);    //  4 MB (aliases dead cos)
    float*    h     = (float*)(ws + 25165824);    //  8 MB (aliases dead cos)
    float*    h2    = (float*)(ws + 33554432);    //  8 MB (aliases dead cos)
    unsigned* maskw = (unsigned*)(ws + 75497472); //  2 MB  [72MB.. area clear of cos]
    int*      ecnt  = (int*)  (ws + 77594624);    // 16384 B
    int*      rcnt  = (int*)  (ws + 77611008);    // 16384 B
    float*    csum  = (float*)(ws + 77627392);    // 16384 B
    float*    rsum  = (float*)(ws + 77643776);    // 16384 B

    // 1. xn = x / max(||x||, eps)
    rownorm_k<<<N, 256, 0, stream>>>(x, xn);
    // 2. cos = xn @ xn^T (f32 — exact ordering preserved from round 0)
    matmul_abt_k<<<dim3(N / BN, N / BM), 256, 0, stream>>>(xn, xn, nullptr, cosm,
                                                           IN_FT, IN_FT, IN_FT, N);
    // 3. mask = (cos > thr) | topk  ->  bitmask
    topk_mask_k<<<N, 256, 0, stream>>>(cosm, maskw);
    // 4. h = x @ proj_w^T + proj_b   (cos region now dead; h aliases it)
    matmul_abt_k<<<dim3(OUT_FT / BN, N / BM), 256, 0, stream>>>(x, proj_w, proj_b, h,
                                                                IN_FT, IN_FT, IN_FT, OUT_FT);
    // 5. sparse structure + L1 sums (deterministic fixed-order scans, no atomics)
    build_cols_k<<<N / 256, 256, 0, stream>>>(maskw, w1, Hmat, elist, eval_, ecnt, csum);
    build_rows_k<<<N / 256, 256, 0, stream>>>(maskw, w2, Hmat, rlist, rval, rcnt, rsum);
    // 6. h2[e,:] = (1/csum[e]) sum_v eval*h[v,:]
    spmm_k<<<N, 256, 0, stream>>>(elist, eval_, ecnt, csum, h, h2);
    // 7. out[v,:] = (1/rsum[v]) sum_e rval*h2[e,:]
    spmm_k<<<N, 256, 0, stream>>>(rlist, rval, rcnt, rsum, h2, out);
}

// Round 4
// 1153.016 us; speedup vs baseline: 1.5258x; 1.5258x over previous
//
#include <hip/hip_runtime.h>
#include <hip/hip_bf16.h>
#include <math.h>

#define N 4096
#define IN_FT 512
#define OUT_FT 512
#define COS_THR 0.5f
#define COS_K 10
#define EPSN 1e-12f
#define CAP 256          // max stored nnz per row/col (actual ~10)
#define NW (N / 32)      // bitmask words per row

#define BM 64
#define BN 64
#define BK 16

// ---------- row-normalize x ----------
__global__ __launch_bounds__(256) void rownorm_k(const float* __restrict__ x,
                                                 float* __restrict__ xn) {
    int row = blockIdx.x;
    const float* xr = x + (size_t)row * IN_FT;
    float s = 0.f;
    for (int j = threadIdx.x; j < IN_FT; j += 256) { float v = xr[j]; s += v * v; }
    __shared__ float red[256];
    red[threadIdx.x] = s; __syncthreads();
    for (int off = 128; off > 0; off >>= 1) {
        if (threadIdx.x < off) red[threadIdx.x] += red[threadIdx.x + off];
        __syncthreads();
    }
    float inv = 1.0f / fmaxf(sqrtf(red[0]), 1e-12f);
    for (int j = threadIdx.x; j < IN_FT; j += 256)
        xn[(size_t)row * IN_FT + j] = xr[j] * inv;
}

// ---------- C[M,N] = A[M,K] @ B[N,K]^T (+bias), f32 ----------
// (byte-identical cos path: top-k selection depends on its exact rounding)
__global__ __launch_bounds__(256) void matmul_abt_k(const float* __restrict__ A,
                                                    const float* __restrict__ B,
                                                    const float* __restrict__ bias,
                                                    float* __restrict__ C,
                                                    int K, int lda, int ldb, int ldc) {
    __shared__ float As[BK][BM + 1];
    __shared__ float Bs[BK][BN + 1];
    int i0 = blockIdx.y * BM, j0 = blockIdx.x * BN;
    int tid = threadIdx.x;
    int tx = tid & 15, ty = tid >> 4;
    float acc[4][4] = {{0.f}};
    for (int k0 = 0; k0 < K; k0 += BK) {
#pragma unroll
        for (int l = 0; l < 4; ++l) {
            int idx = tid + l * 256;
            int m = idx >> 4, k = idx & 15;
            As[k][m] = A[(size_t)(i0 + m) * lda + k0 + k];
        }
#pragma unroll
        for (int l = 0; l < 4; ++l) {
            int idx = tid + l * 256;
            int n = idx >> 4, k = idx & 15;
            Bs[k][n] = B[(size_t)(j0 + n) * ldb + k0 + k];
        }
        __syncthreads();
#pragma unroll
        for (int k = 0; k < BK; ++k) {
            float a[4], b[4];
#pragma unroll
            for (int i = 0; i < 4; ++i) a[i] = As[k][ty * 4 + i];
#pragma unroll
            for (int j = 0; j < 4; ++j) b[j] = Bs[k][tx * 4 + j];
#pragma unroll
            for (int i = 0; i < 4; ++i)
#pragma unroll
                for (int j = 0; j < 4; ++j) acc[i][j] += a[i] * b[j];
        }
        __syncthreads();
    }
#pragma unroll
    for (int i = 0; i < 4; ++i) {
        int r = i0 + ty * 4 + i;
#pragma unroll
        for (int j = 0; j < 4; ++j) {
            int c = j0 + tx * 4 + j;
            float v = acc[i][j];
            if (bias) v += bias[c];
            C[(size_t)r * ldc + c] = v;
        }
    }
}

// ---------- per-row top-k + threshold -> row bitmask + word-transposed bitmask ----------
__global__ __launch_bounds__(256) void topk_mask_k(const float* __restrict__ cosm,
                                                   unsigned* __restrict__ maskw,
                                                   unsigned* __restrict__ maskT) {
    int row = blockIdx.x;
    __shared__ float vals[N];
    __shared__ unsigned char flag[N];
    __shared__ float rv[256];
    __shared__ int ri[256];
    const float* crow = cosm + (size_t)row * N;
    for (int j = threadIdx.x; j < N; j += 256) {
        float v = crow[j];
        vals[j] = v;
        flag[j] = (v > COS_THR) ? 1 : 0;
    }
    __syncthreads();
    for (int t = 0; t < COS_K; ++t) {
        float best = -INFINITY;
        int bidx = 0x7fffffff;
        for (int j = threadIdx.x; j < N; j += 256) {
            float v = vals[j];
            if (v > best) { best = v; bidx = j; }  // ascending j -> lowest idx on tie
        }
        rv[threadIdx.x] = best; ri[threadIdx.x] = bidx;
        __syncthreads();
        for (int off = 128; off > 0; off >>= 1) {
            if (threadIdx.x < off) {
                float v2 = rv[threadIdx.x + off]; int i2 = ri[threadIdx.x + off];
                float v1 = rv[threadIdx.x];       int i1 = ri[threadIdx.x];
                if (v2 > v1 || (v2 == v1 && i2 < i1)) { rv[threadIdx.x] = v2; ri[threadIdx.x] = i2; }
            }
            __syncthreads();
        }
        int w = ri[0];
        if (threadIdx.x == 0) { vals[w] = -INFINITY; flag[w] = 1; }
        __syncthreads();
    }
    for (int wdx = threadIdx.x; wdx < NW; wdx += 256) {
        unsigned bits = 0;
#pragma unroll
        for (int b = 0; b < 32; ++b) bits |= (flag[wdx * 32 + b] ? 1u : 0u) << b;
        maskw[(size_t)row * NW + wdx] = bits;
        maskT[(size_t)wdx * N + row] = bits;   // word-granular transpose
    }
}

// ---------- hyperedge (column) lists: deterministic v-ascending scan ----------
// reads transposed mask: wave's 64 lanes share 2 words -> 2 sequential line
// streams (L1-resident); w1/H gathers coalesced (consecutive e, same v).
__global__ __launch_bounds__(64) void build_cols_k(const unsigned* __restrict__ maskT,
                                                   const float* __restrict__ w1,
                                                   const float* __restrict__ Hmat,
                                                   int* __restrict__ elist,
                                                   float* __restrict__ eval_,
                                                   int* __restrict__ ecnt,
                                                   float* __restrict__ csum) {
    int e = blockIdx.x * 64 + threadIdx.x;
    const unsigned* mcol = maskT + (size_t)(e >> 5) * N;
    unsigned bit = 1u << (e & 31);
    int cnt = 0; float s = 0.f;
#pragma unroll 8
    for (int v = 0; v < N; ++v) {
        if (mcol[v] & bit) {
            float val = w1[(size_t)v * N + e] * Hmat[(size_t)v * N + e];
            if (cnt < CAP) {
                elist[(size_t)e * CAP + cnt] = v;
                eval_[(size_t)e * CAP + cnt] = val;
            }
            s += fabsf(val);
            ++cnt;
        }
    }
    ecnt[e] = cnt < CAP ? cnt : CAP;
    csum[e] = s;
}

// ---------- node (row) lists: deterministic e-ascending scan ----------
__global__ __launch_bounds__(256) void build_rows_k(const unsigned* __restrict__ maskw,
                                                    const float* __restrict__ w2,
                                                    const float* __restrict__ Hmat,
                                                    int* __restrict__ rlist,
                                                    float* __restrict__ rval,
                                                    int* __restrict__ rcnt,
                                                    float* __restrict__ rsum) {
    int v = blockIdx.x * 256 + threadIdx.x;
    const unsigned* mrow = maskw + (size_t)v * NW;
    int cnt = 0; float s = 0.f;
    for (int w = 0; w < NW; ++w) {
        unsigned bits = mrow[w];
        while (bits) {
            int b = __builtin_ctz(bits);
            bits &= bits - 1;
            int e = w * 32 + b;
            float val = w2[(size_t)v * N + e] * Hmat[(size_t)v * N + e];
            if (cnt < CAP) {
                rlist[(size_t)v * CAP + cnt] = e;
                rval[(size_t)v * CAP + cnt] = val;
            }
            s += fabsf(val);
            ++cnt;
        }
    }
    rcnt[v] = cnt < CAP ? cnt : CAP;
    rsum[v] = s;
}

// ---------- dst[i,:] = (1/max(sum[i],eps)) * sum_j val[i,j] * src[list[i,j],:] ----------
__global__ __launch_bounds__(256) void spmm_k(const int* __restrict__ list,
                                              const float* __restrict__ val,
                                              const int* __restrict__ cnt,
                                              const float* __restrict__ sums,
                                              const float* __restrict__ src,
                                              float* __restrict__ dst) {
    int i = blockIdx.x;
    int f = threadIdx.x;
    int c = cnt[i];
    float acc0 = 0.f, acc1 = 0.f;
    for (int t = 0; t < c; ++t) {
        int j = list[(size_t)i * CAP + t];
        float a = val[(size_t)i * CAP + t];
        acc0 += a * src[(size_t)j * OUT_FT + f];
        acc1 += a * src[(size_t)j * OUT_FT + f + 256];
    }
    float sc = 1.0f / fmaxf(sums[i], EPSN);
    dst[(size_t)i * OUT_FT + f] = acc0 * sc;
    dst[(size_t)i * OUT_FT + f + 256] = acc1 * sc;
}

extern "C" void kernel_launch(void* const* d_in, const int* in_sizes, int n_in,
                              void* d_out, int out_size, void* d_ws, size_t ws_size,
                              hipStream_t stream) {
    const float* x      = (const float*)d_in[0];   // [4096,512]
    const float* Hmat   = (const float*)d_in[1];   // [4096,4096]
    const float* proj_w = (const float*)d_in[2];   // [512,512]
    const float* proj_b = (const float*)d_in[3];   // [512]
    const float* w1     = (const float*)d_in[4];   // [4096,4096]
    const float* w2     = (const float*)d_in[5];   // [4096,4096]
    float* out = (float*)d_out;

    char* ws = (char*)d_ws;
    float*    xn    = (float*)(ws + 0);           //  8 MB
    float*    cosm  = (float*)(ws + 8388608);     // 64 MB [8MB..72MB), dead after topk
    int*      elist = (int*)  (ws + 8388608);     //  4 MB (aliases dead cos)
    float*    eval_ = (float*)(ws + 12582912);    //  4 MB (aliases dead cos)
    int*      rlist = (int*)  (ws + 16777216);    //  4 MB (aliases dead cos)
    float*    rval  = (float*)(ws + 20971520);    //  4 MB (aliases dead cos)
    float*    h     = (float*)(ws + 25165824);    //  8 MB (aliases dead cos)
    float*    h2    = (float*)(ws + 33554432);    //  8 MB (aliases dead cos)
    unsigned* maskw = (unsigned*)(ws + 75497472); //  2 MB
    unsigned* maskT = (unsigned*)(ws + 77594624); //  2 MB (word-transposed)
    int*      ecnt  = (int*)  (ws + 79691776);    // 16384 B
    int*      rcnt  = (int*)  (ws + 79708160);    // 16384 B
    float*    csum  = (float*)(ws + 79724544);    // 16384 B
    float*    rsum  = (float*)(ws + 79740928);    // 16384 B

    // 1. xn = x / max(||x||, eps)
    rownorm_k<<<N, 256, 0, stream>>>(x, xn);
    // 2. cos = xn @ xn^T (f32 — exact ordering preserved)
    matmul_abt_k<<<dim3(N / BN, N / BM), 256, 0, stream>>>(xn, xn, nullptr, cosm,
                                                           IN_FT, IN_FT, IN_FT, N);
    // 3. mask -> row bitmask + transposed bitmask
    topk_mask_k<<<N, 256, 0, stream>>>(cosm, maskw, maskT);
    // 4. h = x @ proj_w^T + proj_b   (cos region now dead; h aliases it)
    matmul_abt_k<<<dim3(OUT_FT / BN, N / BM), 256, 0, stream>>>(x, proj_w, proj_b, h,
                                                                IN_FT, IN_FT, IN_FT, OUT_FT);
    // 5. sparse structure + L1 sums (deterministic fixed-order scans, no atomics)
    build_cols_k<<<N / 64, 64, 0, stream>>>(maskT, w1, Hmat, elist, eval_, ecnt, csum);
    build_rows_k<<<N / 256, 256, 0, stream>>>(maskw, w2, Hmat, rlist, rval, rcnt, rsum);
    // 6. h2[e,:] = (1/csum[e]) sum_v eval*h[v,:]
    spmm_k<<<N, 256, 0, stream>>>(elist, eval_, ecnt, csum, h, h2);
    // 7. out[v,:] = (1/rsum[v]) sum_e rval*h2[e,:]
    spmm_k<<<N, 256, 0, stream>>>(rlist, rval, rcnt, rsum, h2, out);
}

// Round 5
// 935.760 us; speedup vs baseline: 1.8801x; 1.2322x over previous
//
#include <hip/hip_runtime.h>
#include <hip/hip_bf16.h>
#include <math.h>

#define N 4096
#define IN_FT 512
#define OUT_FT 512
#define COS_THR 0.5f
#define COS_K 10
#define EPSN 1e-12f
#define CAP 256          // max stored nnz per row/col (actual ~10)
#define NW (N / 32)      // bitmask words per row

#define BM 64
#define BN 64
#define BK 16

// ---------- row-normalize x ----------
__global__ __launch_bounds__(256) void rownorm_k(const float* __restrict__ x,
                                                 float* __restrict__ xn) {
    int row = blockIdx.x;
    const float* xr = x + (size_t)row * IN_FT;
    float s = 0.f;
    for (int j = threadIdx.x; j < IN_FT; j += 256) { float v = xr[j]; s += v * v; }
    __shared__ float red[256];
    red[threadIdx.x] = s; __syncthreads();
    for (int off = 128; off > 0; off >>= 1) {
        if (threadIdx.x < off) red[threadIdx.x] += red[threadIdx.x + off];
        __syncthreads();
    }
    float inv = 1.0f / fmaxf(sqrtf(red[0]), 1e-12f);
    for (int j = threadIdx.x; j < IN_FT; j += 256)
        xn[(size_t)row * IN_FT + j] = xr[j] * inv;
}

// ---------- C[M,N] = A[M,K] @ B[N,K]^T (+bias), f32 ----------
// (byte-identical cos path: top-k selection depends on its exact rounding)
__global__ __launch_bounds__(256) void matmul_abt_k(const float* __restrict__ A,
                                                    const float* __restrict__ B,
                                                    const float* __restrict__ bias,
                                                    float* __restrict__ C,
                                                    int K, int lda, int ldb, int ldc) {
    __shared__ float As[BK][BM + 1];
    __shared__ float Bs[BK][BN + 1];
    int i0 = blockIdx.y * BM, j0 = blockIdx.x * BN;
    int tid = threadIdx.x;
    int tx = tid & 15, ty = tid >> 4;
    float acc[4][4] = {{0.f}};
    for (int k0 = 0; k0 < K; k0 += BK) {
#pragma unroll
        for (int l = 0; l < 4; ++l) {
            int idx = tid + l * 256;
            int m = idx >> 4, k = idx & 15;
            As[k][m] = A[(size_t)(i0 + m) * lda + k0 + k];
        }
#pragma unroll
        for (int l = 0; l < 4; ++l) {
            int idx = tid + l * 256;
            int n = idx >> 4, k = idx & 15;
            Bs[k][n] = B[(size_t)(j0 + n) * ldb + k0 + k];
        }
        __syncthreads();
#pragma unroll
        for (int k = 0; k < BK; ++k) {
            float a[4], b[4];
#pragma unroll
            for (int i = 0; i < 4; ++i) a[i] = As[k][ty * 4 + i];
#pragma unroll
            for (int j = 0; j < 4; ++j) b[j] = Bs[k][tx * 4 + j];
#pragma unroll
            for (int i = 0; i < 4; ++i)
#pragma unroll
                for (int j = 0; j < 4; ++j) acc[i][j] += a[i] * b[j];
        }
        __syncthreads();
    }
#pragma unroll
    for (int i = 0; i < 4; ++i) {
        int r = i0 + ty * 4 + i;
#pragma unroll
        for (int j = 0; j < 4; ++j) {
            int c = j0 + tx * 4 + j;
            float v = acc[i][j];
            if (bias) v += bias[c];
            C[(size_t)r * ldc + c] = v;
        }
    }
}

// ---------- per-row top-k + threshold -> transposed bitmask + row sparse list ----------
// fuses old build_rows_k: flags are already in LDS; ballot-compaction gives
// deterministic e-ascending positions without any serial global-latency scan.
__global__ __launch_bounds__(256) void topk_mask_k(const float* __restrict__ cosm,
                                                   unsigned* __restrict__ maskT,
                                                   const float* __restrict__ w2,
                                                   const float* __restrict__ Hmat,
                                                   int* __restrict__ rlist,
                                                   float* __restrict__ rval,
                                                   int* __restrict__ rcnt,
                                                   float* __restrict__ rsum) {
    int row = blockIdx.x;
    int tid = threadIdx.x;
    __shared__ float vals[N];
    __shared__ unsigned char flag[N];
    __shared__ float rv[256];
    __shared__ int ri[256];
    __shared__ int wcnt[4];
    __shared__ int basev;
    const float* crow = cosm + (size_t)row * N;
    for (int j = tid; j < N; j += 256) {
        float v = crow[j];
        vals[j] = v;
        flag[j] = (v > COS_THR) ? 1 : 0;
    }
    __syncthreads();
    // --- iterative top-K (exact, matches jax.lax.top_k selection) ---
    for (int t = 0; t < COS_K; ++t) {
        float best = -INFINITY;
        int bidx = 0x7fffffff;
        for (int j = tid; j < N; j += 256) {
            float v = vals[j];
            if (v > best) { best = v; bidx = j; }  // ascending j -> lowest idx on tie
        }
        rv[tid] = best; ri[tid] = bidx;
        __syncthreads();
        for (int off = 128; off > 0; off >>= 1) {
            if (tid < off) {
                float v2 = rv[tid + off]; int i2 = ri[tid + off];
                float v1 = rv[tid];       int i1 = ri[tid];
                if (v2 > v1 || (v2 == v1 && i2 < i1)) { rv[tid] = v2; ri[tid] = i2; }
            }
            __syncthreads();
        }
        int w = ri[0];
        if (tid == 0) { vals[w] = -INFINITY; flag[w] = 1; }
        __syncthreads();
    }
    // --- transposed bitmask for build_cols ---
    for (int wdx = tid; wdx < NW; wdx += 256) {
        unsigned bits = 0;
#pragma unroll
        for (int b = 0; b < 32; ++b) bits |= (flag[wdx * 32 + b] ? 1u : 0u) << b;
        maskT[(size_t)wdx * N + row] = bits;
    }
    // --- row sparse list via ballot compaction (deterministic e-ascending) ---
    int wid = tid >> 6, lane = tid & 63;
    float s_acc = 0.f;
    if (tid == 0) basev = 0;
    __syncthreads();
    for (int c = 0; c < 16; ++c) {
        int j = c * 256 + tid;
        bool f = flag[j] != 0;
        unsigned long long b = __ballot(f);
        if (lane == 0) wcnt[wid] = __popcll(b);
        __syncthreads();
        int off = basev;
        for (int w = 0; w < wid; ++w) off += wcnt[w];
        int pos = off + __popcll(b & ((1ull << lane) - 1ull));
        if (f) {
            size_t ofs = (size_t)row * N + j;
            float val = w2[ofs] * Hmat[ofs];
            if (pos < CAP) {
                rlist[(size_t)row * CAP + pos] = j;
                rval[(size_t)row * CAP + pos] = val;
            }
            s_acc += fabsf(val);
        }
        __syncthreads();
        if (tid == 0) basev += wcnt[0] + wcnt[1] + wcnt[2] + wcnt[3];
        __syncthreads();
    }
    // --- block tree-reduce |.| sum (nonneg, ~10 terms: order-insensitive) ---
    rv[tid] = s_acc;
    __syncthreads();
    for (int off = 128; off > 0; off >>= 1) {
        if (tid < off) rv[tid] += rv[tid + off];
        __syncthreads();
    }
    if (tid == 0) {
        rcnt[row] = basev < CAP ? basev : CAP;
        rsum[row] = rv[0];
    }
}

// ---------- hyperedge (column) lists: LDS-staged block scan ----------
// block = 8 mask words = 256 columns (e = blockIdx.x*256+tid). Per 256-v
// chunk: 8 coalesced 1KB loads into LDS (in flight together), then each
// thread scans its word-column from LDS (broadcast reads, no global latency).
__global__ __launch_bounds__(256) void build_cols_k(const unsigned* __restrict__ maskT,
                                                    const float* __restrict__ w1,
                                                    const float* __restrict__ Hmat,
                                                    int* __restrict__ elist,
                                                    float* __restrict__ eval_,
                                                    int* __restrict__ ecnt,
                                                    float* __restrict__ csum) {
    __shared__ unsigned chunk[8][256];
    int tid = threadIdx.x;
    int e = blockIdx.x * 256 + tid;
    int wl = tid >> 5;                 // local word 0..7
    unsigned bit = 1u << (tid & 31);
    int wbase = blockIdx.x * 8;
    int cnt = 0; float s = 0.f;
    for (int v0 = 0; v0 < N; v0 += 256) {
#pragma unroll
        for (int i = 0; i < 8; ++i)
            chunk[i][tid] = maskT[(size_t)(wbase + i) * N + v0 + tid];
        __syncthreads();
#pragma unroll 4
        for (int v = 0; v < 256; ++v) {
            if (chunk[wl][v] & bit) {
                size_t ofs = (size_t)(v0 + v) * N + e;
                float val = w1[ofs] * Hmat[ofs];
                if (cnt < CAP) {
                    elist[(size_t)e * CAP + cnt] = v0 + v;
                    eval_[(size_t)e * CAP + cnt] = val;
                }
                s += fabsf(val);
                ++cnt;
            }
        }
        __syncthreads();
    }
    ecnt[e] = cnt < CAP ? cnt : CAP;
    csum[e] = s;
}

// ---------- dst[i,:] = (1/max(sum[i],eps)) * sum_j val[i,j] * src[list[i,j],:] ----------
__global__ __launch_bounds__(256) void spmm_k(const int* __restrict__ list,
                                              const float* __restrict__ val,
                                              const int* __restrict__ cnt,
                                              const float* __restrict__ sums,
                                              const float* __restrict__ src,
                                              float* __restrict__ dst) {
    int i = blockIdx.x;
    int f = threadIdx.x;
    int c = cnt[i];
    float acc0 = 0.f, acc1 = 0.f;
    for (int t = 0; t < c; ++t) {
        int j = list[(size_t)i * CAP + t];
        float a = val[(size_t)i * CAP + t];
        acc0 += a * src[(size_t)j * OUT_FT + f];
        acc1 += a * src[(size_t)j * OUT_FT + f + 256];
    }
    float sc = 1.0f / fmaxf(sums[i], EPSN);
    dst[(size_t)i * OUT_FT + f] = acc0 * sc;
    dst[(size_t)i * OUT_FT + f + 256] = acc1 * sc;
}

extern "C" void kernel_launch(void* const* d_in, const int* in_sizes, int n_in,
                              void* d_out, int out_size, void* d_ws, size_t ws_size,
                              hipStream_t stream) {
    const float* x      = (const float*)d_in[0];   // [4096,512]
    const float* Hmat   = (const float*)d_in[1];   // [4096,4096]
    const float* proj_w = (const float*)d_in[2];   // [512,512]
    const float* proj_b = (const float*)d_in[3];   // [512]
    const float* w1     = (const float*)d_in[4];   // [4096,4096]
    const float* w2     = (const float*)d_in[5];   // [4096,4096]
    float* out = (float*)d_out;

    char* ws = (char*)d_ws;
    float*    xn    = (float*)(ws + 0);           //  8 MB
    float*    cosm  = (float*)(ws + 8388608);     // 64 MB [8MB..72MB), dead after topk
    int*      elist = (int*)  (ws + 8388608);     //  4 MB (aliases dead cos)
    float*    eval_ = (float*)(ws + 12582912);    //  4 MB (aliases dead cos)
    int*      rlist = (int*)  (ws + 16777216);    //  4 MB (aliases dead cos)  -- NOTE: written by topk AFTER cos consumed? see below
    float*    rval  = (float*)(ws + 20971520);    //  4 MB (aliases dead cos)
    float*    h     = (float*)(ws + 25165824);    //  8 MB (aliases dead cos)
    float*    h2    = (float*)(ws + 33554432);    //  8 MB (aliases dead cos)
    unsigned* maskT = (unsigned*)(ws + 75497472); //  2 MB (word-transposed), outside cos
    int*      ecnt  = (int*)  (ws + 77594624);    // 16384 B
    int*      rcnt  = (int*)  (ws + 77611008);    // 16384 B
    float*    csum  = (float*)(ws + 77627392);    // 16384 B
    float*    rsum  = (float*)(ws + 77643776);    // 16384 B
    // aliasing safety: topk_mask_k writes rlist/rval which alias cosm rows
    // 2048..3071; but each topk block reads ONLY its own cos row fully into
    // LDS before any write happens?  NO — blocks run concurrently: block 100
    // could write rlist while block 3000 still needs cos row 3000.  rlist
    // spans cos rows 2048..3071 -> those rows' topk blocks might read
    // clobbered data.  => place rlist/rval OUTSIDE the cos region instead:
    rlist = (int*)  (ws + 77660160);              //  4 MB  [74.06MB..78.06MB)
    rval  = (float*)(ws + 81854464);              //  4 MB  [78.06MB..82.06MB)

    // 1. xn = x / max(||x||, eps)
    rownorm_k<<<N, 256, 0, stream>>>(x, xn);
    // 2. cos = xn @ xn^T (f32 — exact ordering preserved)
    matmul_abt_k<<<dim3(N / BN, N / BM), 256, 0, stream>>>(xn, xn, nullptr, cosm,
                                                           IN_FT, IN_FT, IN_FT, N);
    // 3. topk/threshold -> maskT + row sparse lists (build_rows fused here)
    topk_mask_k<<<N, 256, 0, stream>>>(cosm, maskT, w2, Hmat, rlist, rval, rcnt, rsum);
    // 4. h = x @ proj_w^T + proj_b   (cos region now dead; h aliases it)
    matmul_abt_k<<<dim3(OUT_FT / BN, N / BM), 256, 0, stream>>>(x, proj_w, proj_b, h,
                                                                IN_FT, IN_FT, IN_FT, OUT_FT);
    // 5. column sparse lists (LDS-staged coalesced scan)
    build_cols_k<<<N / 256, 256, 0, stream>>>(maskT, w1, Hmat, elist, eval_, ecnt, csum);
    // 6. h2[e,:] = (1/csum[e]) sum_v eval*h[v,:]
    spmm_k<<<N, 256, 0, stream>>>(elist, eval_, ecnt, csum, h, h2);
    // 7. out[v,:] = (1/rsum[v]) sum_e rval*h2[e,:]
    spmm_k<<<N, 256, 0, stream>>>(rlist, rval, rcnt, rsum, h2, out);
}

// Round 6
// 586.107 us; speedup vs baseline: 3.0017x; 1.5966x over previous
//
#include <hip/hip_runtime.h>
#include <hip/hip_bf16.h>
#include <math.h>

#define N 4096
#define IN_FT 512
#define OUT_FT 512
#define COS_THR 0.5f
#define COS_K 10
#define EPSN 1e-12f
#define CAP 256          // max stored nnz per row/col (actual ~10)
#define NW (N / 32)      // bitmask words per row

#define BM 64
#define BN 64
#define BK 16

// ---------- row-normalize x ----------
__global__ __launch_bounds__(256) void rownorm_k(const float* __restrict__ x,
                                                 float* __restrict__ xn) {
    int row = blockIdx.x;
    const float* xr = x + (size_t)row * IN_FT;
    float s = 0.f;
    for (int j = threadIdx.x; j < IN_FT; j += 256) { float v = xr[j]; s += v * v; }
    __shared__ float red[256];
    red[threadIdx.x] = s; __syncthreads();
    for (int off = 128; off > 0; off >>= 1) {
        if (threadIdx.x < off) red[threadIdx.x] += red[threadIdx.x + off];
        __syncthreads();
    }
    float inv = 1.0f / fmaxf(sqrtf(red[0]), 1e-12f);
    for (int j = threadIdx.x; j < IN_FT; j += 256)
        xn[(size_t)row * IN_FT + j] = xr[j] * inv;
}

// ---------- C[M,N] = A[M,K] @ B[N,K]^T (+bias), f32 ----------
// (byte-identical cos path: top-k selection depends on its exact rounding)
__global__ __launch_bounds__(256) void matmul_abt_k(const float* __restrict__ A,
                                                    const float* __restrict__ B,
                                                    const float* __restrict__ bias,
                                                    float* __restrict__ C,
                                                    int K, int lda, int ldb, int ldc) {
    __shared__ float As[BK][BM + 1];
    __shared__ float Bs[BK][BN + 1];
    int i0 = blockIdx.y * BM, j0 = blockIdx.x * BN;
    int tid = threadIdx.x;
    int tx = tid & 15, ty = tid >> 4;
    float acc[4][4] = {{0.f}};
    for (int k0 = 0; k0 < K; k0 += BK) {
#pragma unroll
        for (int l = 0; l < 4; ++l) {
            int idx = tid + l * 256;
            int m = idx >> 4, k = idx & 15;
            As[k][m] = A[(size_t)(i0 + m) * lda + k0 + k];
        }
#pragma unroll
        for (int l = 0; l < 4; ++l) {
            int idx = tid + l * 256;
            int n = idx >> 4, k = idx & 15;
            Bs[k][n] = B[(size_t)(j0 + n) * ldb + k0 + k];
        }
        __syncthreads();
#pragma unroll
        for (int k = 0; k < BK; ++k) {
            float a[4], b[4];
#pragma unroll
            for (int i = 0; i < 4; ++i) a[i] = As[k][ty * 4 + i];
#pragma unroll
            for (int j = 0; j < 4; ++j) b[j] = Bs[k][tx * 4 + j];
#pragma unroll
            for (int i = 0; i < 4; ++i)
#pragma unroll
                for (int j = 0; j < 4; ++j) acc[i][j] += a[i] * b[j];
        }
        __syncthreads();
    }
#pragma unroll
    for (int i = 0; i < 4; ++i) {
        int r = i0 + ty * 4 + i;
#pragma unroll
        for (int j = 0; j < 4; ++j) {
            int c = j0 + tx * 4 + j;
            float v = acc[i][j];
            if (bias) v += bias[c];
            C[(size_t)r * ldc + c] = v;
        }
    }
}

// ---------- per-row top-k + threshold -> transposed bitmask + row sparse list ----------
__global__ __launch_bounds__(256) void topk_mask_k(const float* __restrict__ cosm,
                                                   unsigned* __restrict__ maskT,
                                                   const float* __restrict__ w2,
                                                   const float* __restrict__ Hmat,
                                                   int* __restrict__ rlist,
                                                   float* __restrict__ rval,
                                                   int* __restrict__ rcnt) {
    int row = blockIdx.x;
    int tid = threadIdx.x;
    __shared__ float vals[N];
    __shared__ unsigned char flag[N];
    __shared__ float rv[256];
    __shared__ int ri[256];
    __shared__ int wcnt[4];
    __shared__ int basev;
    const float* crow = cosm + (size_t)row * N;
    for (int j = tid; j < N; j += 256) {
        float v = crow[j];
        vals[j] = v;
        flag[j] = (v > COS_THR) ? 1 : 0;
    }
    __syncthreads();
    // --- iterative top-K (exact, matches jax.lax.top_k selection) ---
    for (int t = 0; t < COS_K; ++t) {
        float best = -INFINITY;
        int bidx = 0x7fffffff;
        for (int j = tid; j < N; j += 256) {
            float v = vals[j];
            if (v > best) { best = v; bidx = j; }  // ascending j -> lowest idx on tie
        }
        rv[tid] = best; ri[tid] = bidx;
        __syncthreads();
        for (int off = 128; off > 0; off >>= 1) {
            if (tid < off) {
                float v2 = rv[tid + off]; int i2 = ri[tid + off];
                float v1 = rv[tid];       int i1 = ri[tid];
                if (v2 > v1 || (v2 == v1 && i2 < i1)) { rv[tid] = v2; ri[tid] = i2; }
            }
            __syncthreads();
        }
        int w = ri[0];
        if (tid == 0) { vals[w] = -INFINITY; flag[w] = 1; }
        __syncthreads();
    }
    // --- transposed bitmask for the column build ---
    for (int wdx = tid; wdx < NW; wdx += 256) {
        unsigned bits = 0;
#pragma unroll
        for (int b = 0; b < 32; ++b) bits |= (flag[wdx * 32 + b] ? 1u : 0u) << b;
        maskT[(size_t)wdx * N + row] = bits;
    }
    // --- row sparse list via ballot compaction (deterministic e-ascending) ---
    int wid = tid >> 6, lane = tid & 63;
    if (tid == 0) basev = 0;
    __syncthreads();
    for (int c = 0; c < 16; ++c) {
        int j = c * 256 + tid;
        bool f = flag[j] != 0;
        unsigned long long b = __ballot(f);
        if (lane == 0) wcnt[wid] = __popcll(b);
        __syncthreads();
        int off = basev;
        for (int w = 0; w < wid; ++w) off += wcnt[w];
        int pos = off + __popcll(b & ((1ull << lane) - 1ull));
        if (f && pos < CAP) {
            size_t ofs = (size_t)row * N + j;
            rlist[(size_t)row * CAP + pos] = j;
            rval[(size_t)row * CAP + pos] = w2[ofs] * Hmat[ofs];
        }
        __syncthreads();
        if (tid == 0) basev += wcnt[0] + wcnt[1] + wcnt[2] + wcnt[3];
        __syncthreads();
    }
    if (tid == 0) rcnt[row] = basev < CAP ? basev : CAP;
}

// ---------- column build pass 1: per-(v-chunk, e) bit counts ----------
// grid (16 e-blocks, 16 v-chunks): 256 blocks -> all CUs; scan out of LDS.
__global__ __launch_bounds__(256) void count_cols_k(const unsigned* __restrict__ maskT,
                                                    int* __restrict__ cnt16) {
    __shared__ unsigned ch[8][256];
    int tid = threadIdx.x;
    int eb = blockIdx.x, chunk = blockIdx.y;
    int wbase = eb * 8, v0 = chunk * 256;
#pragma unroll
    for (int i = 0; i < 8; ++i)
        ch[i][tid] = maskT[(size_t)(wbase + i) * N + v0 + tid];
    __syncthreads();
    int wl = tid >> 5, bp = tid & 31;
    int cnt = 0;
#pragma unroll 8
    for (int v = 0; v < 256; ++v) cnt += (ch[wl][v] >> bp) & 1;
    cnt16[chunk * N + eb * 256 + tid] = cnt;
}

// ---------- column build pass 2: fill at prefix offsets (deterministic) ----------
// per-thread serial gather chain is ~0.65 loads (vs ~10 before): latency gone.
__global__ __launch_bounds__(256) void fill_cols_k(const unsigned* __restrict__ maskT,
                                                   const int* __restrict__ cnt16,
                                                   const float* __restrict__ w1,
                                                   const float* __restrict__ Hmat,
                                                   int* __restrict__ elist,
                                                   float* __restrict__ eval_,
                                                   int* __restrict__ ecnt) {
    __shared__ unsigned ch[8][256];
    int tid = threadIdx.x;
    int eb = blockIdx.x, chunk = blockIdx.y;
    int e = eb * 256 + tid;
    int wbase = eb * 8, v0 = chunk * 256;
#pragma unroll
    for (int i = 0; i < 8; ++i)
        ch[i][tid] = maskT[(size_t)(wbase + i) * N + v0 + tid];
    int pos = 0;
    for (int c = 0; c < chunk; ++c) pos += cnt16[c * N + e];
    __syncthreads();
    int wl = tid >> 5;
    unsigned bit = 1u << (tid & 31);
    for (int v = 0; v < 256; ++v) {
        if (ch[wl][v] & bit) {
            if (pos < CAP) {
                size_t ofs = (size_t)(v0 + v) * N + e;
                elist[(size_t)e * CAP + pos] = v0 + v;
                eval_[(size_t)e * CAP + pos] = w1[ofs] * Hmat[ofs];
            }
            ++pos;
        }
    }
    if (chunk == 15) ecnt[e] = pos < CAP ? pos : CAP;  // pos == total nnz of column e
}

// ---------- dst[i,:] = (1/max(sum_t |val|,eps)) * sum_t val*src[list[t],:] ----------
// L1 sum computed here from the list (fixed ascending order, ~10 nonneg terms).
__global__ __launch_bounds__(256) void spmm_k(const int* __restrict__ list,
                                              const float* __restrict__ val,
                                              const int* __restrict__ cnt,
                                              const float* __restrict__ src,
                                              float* __restrict__ dst) {
    int i = blockIdx.x;
    int f = threadIdx.x;
    int c = cnt[i];
    float ssum = 0.f;
    for (int t = 0; t < c; ++t) ssum += fabsf(val[(size_t)i * CAP + t]);
    float acc0 = 0.f, acc1 = 0.f;
    for (int t = 0; t < c; ++t) {
        int j = list[(size_t)i * CAP + t];
        float a = val[(size_t)i * CAP + t];
        acc0 += a * src[(size_t)j * OUT_FT + f];
        acc1 += a * src[(size_t)j * OUT_FT + f + 256];
    }
    float sc = 1.0f / fmaxf(ssum, EPSN);
    dst[(size_t)i * OUT_FT + f] = acc0 * sc;
    dst[(size_t)i * OUT_FT + f + 256] = acc1 * sc;
}

extern "C" void kernel_launch(void* const* d_in, const int* in_sizes, int n_in,
                              void* d_out, int out_size, void* d_ws, size_t ws_size,
                              hipStream_t stream) {
    const float* x      = (const float*)d_in[0];   // [4096,512]
    const float* Hmat   = (const float*)d_in[1];   // [4096,4096]
    const float* proj_w = (const float*)d_in[2];   // [512,512]
    const float* proj_b = (const float*)d_in[3];   // [512]
    const float* w1     = (const float*)d_in[4];   // [4096,4096]
    const float* w2     = (const float*)d_in[5];   // [4096,4096]
    float* out = (float*)d_out;

    char* ws = (char*)d_ws;
    float*    xn    = (float*)(ws + 0);           //  8 MB
    float*    cosm  = (float*)(ws + 8388608);     // 64 MB [8MB..72MB), dead after topk
    int*      elist = (int*)  (ws + 8388608);     //  4 MB (aliases dead cos; written post-topk)
    float*    eval_ = (float*)(ws + 12582912);    //  4 MB (aliases dead cos)
    float*    h     = (float*)(ws + 25165824);    //  8 MB (aliases dead cos)
    float*    h2    = (float*)(ws + 33554432);    //  8 MB (aliases dead cos)
    unsigned* maskT = (unsigned*)(ws + 75497472); //  2 MB (outside cos: topk writes live)
    int*      ecnt  = (int*)  (ws + 77594624);    // 16 KB
    int*      rcnt  = (int*)  (ws + 77611008);    // 16 KB
    int*      rlist = (int*)  (ws + 77660160);    //  4 MB (outside cos: topk writes live)
    float*    rval  = (float*)(ws + 81854464);    //  4 MB (outside cos)
    int*      cnt16 = (int*)  (ws + 86048768);    // 256 KB [16][4096]

    // 1. xn = x / max(||x||, eps)
    rownorm_k<<<N, 256, 0, stream>>>(x, xn);
    // 2. cos = xn @ xn^T (f32 — exact ordering preserved)
    matmul_abt_k<<<dim3(N / BN, N / BM), 256, 0, stream>>>(xn, xn, nullptr, cosm,
                                                           IN_FT, IN_FT, IN_FT, N);
    // 3. topk/threshold -> maskT + row sparse lists
    topk_mask_k<<<N, 256, 0, stream>>>(cosm, maskT, w2, Hmat, rlist, rval, rcnt);
    // 4. h = x @ proj_w^T + proj_b   (cos region now dead; h aliases it)
    matmul_abt_k<<<dim3(OUT_FT / BN, N / BM), 256, 0, stream>>>(x, proj_w, proj_b, h,
                                                                IN_FT, IN_FT, IN_FT, OUT_FT);
    // 5. column lists: count -> fill at prefix offsets (256 blocks each)
    count_cols_k<<<dim3(16, 16), 256, 0, stream>>>(maskT, cnt16);
    fill_cols_k<<<dim3(16, 16), 256, 0, stream>>>(maskT, cnt16, w1, Hmat, elist, eval_, ecnt);
    // 6. h2[e,:] = normalize . gather-sum over column lists
    spmm_k<<<N, 256, 0, stream>>>(elist, eval_, ecnt, h, h2);
    // 7. out[v,:] = normalize . gather-sum over row lists
    spmm_k<<<N, 256, 0, stream>>>(rlist, rval, rcnt, h2, out);
}

// Round 7
// 392.438 us; speedup vs baseline: 4.4831x; 1.4935x over previous
//
#include <hip/hip_runtime.h>
#include <hip/hip_bf16.h>
#include <math.h>

#define N 4096
#define IN_FT 512
#define OUT_FT 512
#define COS_THR 0.5f
#define COS_K 10
#define EPSN 1e-12f
#define CAP 256          // max stored nnz per row/col (actual ~10)
#define NW (N / 32)      // bitmask words per row

#define BM 64
#define BN 64
#define BK 16

#define CB 128           // cos tile
#define CK 16            // cos k-step
#define CNB (N / CB)     // 32 cos block-rows

// ---------- row-normalize x ----------
__global__ __launch_bounds__(256) void rownorm_k(const float* __restrict__ x,
                                                 float* __restrict__ xn) {
    int row = blockIdx.x;
    const float* xr = x + (size_t)row * IN_FT;
    float s = 0.f;
    for (int j = threadIdx.x; j < IN_FT; j += 256) { float v = xr[j]; s += v * v; }
    __shared__ float red[256];
    red[threadIdx.x] = s; __syncthreads();
    for (int off = 128; off > 0; off >>= 1) {
        if (threadIdx.x < off) red[threadIdx.x] += red[threadIdx.x + off];
        __syncthreads();
    }
    float inv = 1.0f / fmaxf(sqrtf(red[0]), 1e-12f);
    for (int j = threadIdx.x; j < IN_FT; j += 256)
        xn[(size_t)row * IN_FT + j] = xr[j] * inv;
}

// ---------- generic C = A @ B^T + bias (used for proj only; unchanged) ----------
__global__ __launch_bounds__(256) void matmul_abt_k(const float* __restrict__ A,
                                                    const float* __restrict__ B,
                                                    const float* __restrict__ bias,
                                                    float* __restrict__ C,
                                                    int K, int lda, int ldb, int ldc) {
    __shared__ float As[BK][BM + 1];
    __shared__ float Bs[BK][BN + 1];
    int i0 = blockIdx.y * BM, j0 = blockIdx.x * BN;
    int tid = threadIdx.x;
    int tx = tid & 15, ty = tid >> 4;
    float acc[4][4] = {{0.f}};
    for (int k0 = 0; k0 < K; k0 += BK) {
#pragma unroll
        for (int l = 0; l < 4; ++l) {
            int idx = tid + l * 256;
            int m = idx >> 4, k = idx & 15;
            As[k][m] = A[(size_t)(i0 + m) * lda + k0 + k];
        }
#pragma unroll
        for (int l = 0; l < 4; ++l) {
            int idx = tid + l * 256;
            int n = idx >> 4, k = idx & 15;
            Bs[k][n] = B[(size_t)(j0 + n) * ldb + k0 + k];
        }
        __syncthreads();
#pragma unroll
        for (int k = 0; k < BK; ++k) {
            float a[4], b[4];
#pragma unroll
            for (int i = 0; i < 4; ++i) a[i] = As[k][ty * 4 + i];
#pragma unroll
            for (int j = 0; j < 4; ++j) b[j] = Bs[k][tx * 4 + j];
#pragma unroll
            for (int i = 0; i < 4; ++i)
#pragma unroll
                for (int j = 0; j < 4; ++j) acc[i][j] += a[i] * b[j];
        }
        __syncthreads();
    }
#pragma unroll
    for (int i = 0; i < 4; ++i) {
        int r = i0 + ty * 4 + i;
#pragma unroll
        for (int j = 0; j < 4; ++j) {
            int c = j0 + tx * 4 + j;
            float v = acc[i][j];
            if (bias) v += bias[c];
            C[(size_t)r * ldc + c] = v;
        }
    }
}

// ---------- symmetric cos GEMM: upper-triangular 128-blocks only ----------
// Per-element accumulation chain (strict ascending k, one FMA per k) is
// bit-identical to matmul_abt_k -> top-k selections cannot change.
__global__ __launch_bounds__(256) void cos_sym_k(const float* __restrict__ A,
                                                 float* __restrict__ C) {
    __shared__ float As[CK][CB + 4];
    __shared__ float Bs[CK][CB + 4];
    int t = blockIdx.x;                       // 0 .. 527
    int by = 0;
    while (t >= CNB - by) { t -= CNB - by; ++by; }
    int bx = by + t;                          // by <= bx
    int i0 = by * CB, j0 = bx * CB;
    int tid = threadIdx.x;
    int tx = tid & 15, ty = tid >> 4;
    int sm = tid >> 1;                        // staging row 0..127
    int sk = (tid & 1) * 8;                   // staging k offset 0/8
    float acc[8][8] = {{0.f}};
    for (int k0 = 0; k0 < IN_FT; k0 += CK) {
        float4 a0 = *(const float4*)&A[(size_t)(i0 + sm) * IN_FT + k0 + sk];
        float4 a1 = *(const float4*)&A[(size_t)(i0 + sm) * IN_FT + k0 + sk + 4];
        float4 b0 = *(const float4*)&A[(size_t)(j0 + sm) * IN_FT + k0 + sk];
        float4 b1 = *(const float4*)&A[(size_t)(j0 + sm) * IN_FT + k0 + sk + 4];
        __syncthreads();                      // previous iter's reads done
        As[sk + 0][sm] = a0.x; As[sk + 1][sm] = a0.y;
        As[sk + 2][sm] = a0.z; As[sk + 3][sm] = a0.w;
        As[sk + 4][sm] = a1.x; As[sk + 5][sm] = a1.y;
        As[sk + 6][sm] = a1.z; As[sk + 7][sm] = a1.w;
        Bs[sk + 0][sm] = b0.x; Bs[sk + 1][sm] = b0.y;
        Bs[sk + 2][sm] = b0.z; Bs[sk + 3][sm] = b0.w;
        Bs[sk + 4][sm] = b1.x; Bs[sk + 5][sm] = b1.y;
        Bs[sk + 6][sm] = b1.z; Bs[sk + 7][sm] = b1.w;
        __syncthreads();
#pragma unroll
        for (int k = 0; k < CK; ++k) {
            float a[8], b[8];
#pragma unroll
            for (int i = 0; i < 8; ++i) a[i] = As[k][ty * 8 + i];
#pragma unroll
            for (int j = 0; j < 8; ++j) b[j] = Bs[k][tx * 8 + j];
#pragma unroll
            for (int i = 0; i < 8; ++i)
#pragma unroll
                for (int j = 0; j < 8; ++j) acc[i][j] += a[i] * b[j];
        }
    }
#pragma unroll
    for (int i = 0; i < 8; ++i) {
        int r = i0 + ty * 8 + i;
#pragma unroll
        for (int j = 0; j < 8; ++j)
            C[(size_t)r * N + j0 + tx * 8 + j] = acc[i][j];
    }
}

// ---------- mirror strict-lower 128-blocks from upper (LDS transpose) ----------
__global__ __launch_bounds__(256) void mirror_k(float* __restrict__ C) {
    __shared__ float tile[64][65];
    int t = blockIdx.x;                       // 0 .. 495
    int by = 0;
    while (t >= CNB - 1 - by) { t -= CNB - 1 - by; ++by; }
    int bx = by + 1 + t;                      // by < bx
    int i0 = by * CB, j0 = bx * CB;
    int tid = threadIdx.x;
    int lr = tid >> 6;                        // 0..3
    int lc = tid & 63;
#pragma unroll
    for (int s = 0; s < 4; ++s) {
        int ri = i0 + (s >> 1) * 64, cj = j0 + (s & 1) * 64;
        __syncthreads();
#pragma unroll
        for (int p = 0; p < 16; ++p)
            tile[p * 4 + lr][lc] = C[(size_t)(ri + p * 4 + lr) * N + cj + lc];
        __syncthreads();
#pragma unroll
        for (int p = 0; p < 16; ++p)
            C[(size_t)(cj + p * 4 + lr) * N + ri + lc] = tile[lc][p * 4 + lr];
    }
}

// ---------- per-row top-k + threshold -> transposed bitmask + row sparse list ----------
__global__ __launch_bounds__(256) void topk_mask_k(const float* __restrict__ cosm,
                                                   unsigned* __restrict__ maskT,
                                                   const float* __restrict__ w2,
                                                   const float* __restrict__ Hmat,
                                                   int* __restrict__ rlist,
                                                   float* __restrict__ rval,
                                                   int* __restrict__ rcnt) {
    int row = blockIdx.x;
    int tid = threadIdx.x;
    __shared__ float vals[N];
    __shared__ unsigned char flag[N];
    __shared__ float wbv[4];
    __shared__ int wbi[4];
    __shared__ int wcnt[4];
    __shared__ int basev;
    int lane = tid & 63, wid = tid >> 6;
    const float* crow = cosm + (size_t)row * N;
    for (int j = tid; j < N; j += 256) {
        float v = crow[j];
        vals[j] = v;
        flag[j] = (v > COS_THR) ? 1 : 0;
    }
    __syncthreads();
    // --- iterative top-K: same comparisons/tie-break as before, shfl reduce ---
    for (int t = 0; t < COS_K; ++t) {
        float best = -INFINITY;
        int bidx = 0x7fffffff;
        for (int j = tid; j < N; j += 256) {
            float v = vals[j];
            if (v > best) { best = v; bidx = j; }  // ascending j -> lowest idx on tie
        }
#pragma unroll
        for (int off = 32; off > 0; off >>= 1) {
            float v2 = __shfl_xor(best, off);
            int i2 = __shfl_xor(bidx, off);
            if (v2 > best || (v2 == best && i2 < bidx)) { best = v2; bidx = i2; }
        }
        if (lane == 0) { wbv[wid] = best; wbi[wid] = bidx; }
        __syncthreads();
        float fb = wbv[0]; int fi = wbi[0];
#pragma unroll
        for (int w = 1; w < 4; ++w) {
            float v2 = wbv[w]; int i2 = wbi[w];
            if (v2 > fb || (v2 == fb && i2 < fi)) { fb = v2; fi = i2; }
        }
        if (tid == 0) { vals[fi] = -INFINITY; flag[fi] = 1; }
        __syncthreads();
    }
    // --- transposed bitmask for the column build ---
    for (int wdx = tid; wdx < NW; wdx += 256) {
        unsigned bits = 0;
#pragma unroll
        for (int b = 0; b < 32; ++b) bits |= (flag[wdx * 32 + b] ? 1u : 0u) << b;
        maskT[(size_t)wdx * N + row] = bits;
    }
    // --- row sparse list via ballot compaction (deterministic e-ascending) ---
    if (tid == 0) basev = 0;
    __syncthreads();
    for (int c = 0; c < 16; ++c) {
        int j = c * 256 + tid;
        bool f = flag[j] != 0;
        unsigned long long b = __ballot(f);
        if (lane == 0) wcnt[wid] = __popcll(b);
        __syncthreads();
        int off = basev;
        for (int w = 0; w < wid; ++w) off += wcnt[w];
        int pos = off + __popcll(b & ((1ull << lane) - 1ull));
        if (f && pos < CAP) {
            size_t ofs = (size_t)row * N + j;
            rlist[(size_t)row * CAP + pos] = j;
            rval[(size_t)row * CAP + pos] = w2[ofs] * Hmat[ofs];
        }
        __syncthreads();
        if (tid == 0) basev += wcnt[0] + wcnt[1] + wcnt[2] + wcnt[3];
        __syncthreads();
    }
    if (tid == 0) rcnt[row] = basev < CAP ? basev : CAP;
}

// ---------- column build pass 1: per-(v-chunk, e) bit counts ----------
__global__ __launch_bounds__(256) void count_cols_k(const unsigned* __restrict__ maskT,
                                                    int* __restrict__ cnt16) {
    __shared__ unsigned ch[8][256];
    int tid = threadIdx.x;
    int eb = blockIdx.x, chunk = blockIdx.y;
    int wbase = eb * 8, v0 = chunk * 256;
#pragma unroll
    for (int i = 0; i < 8; ++i)
        ch[i][tid] = maskT[(size_t)(wbase + i) * N + v0 + tid];
    __syncthreads();
    int wl = tid >> 5, bp = tid & 31;
    int cnt = 0;
#pragma unroll 8
    for (int v = 0; v < 256; ++v) cnt += (ch[wl][v] >> bp) & 1;
    cnt16[chunk * N + eb * 256 + tid] = cnt;
}

// ---------- column build pass 2: fill at prefix offsets (deterministic) ----------
__global__ __launch_bounds__(256) void fill_cols_k(const unsigned* __restrict__ maskT,
                                                   const int* __restrict__ cnt16,
                                                   const float* __restrict__ w1,
                                                   const float* __restrict__ Hmat,
                                                   int* __restrict__ elist,
                                                   float* __restrict__ eval_,
                                                   int* __restrict__ ecnt) {
    __shared__ unsigned ch[8][256];
    int tid = threadIdx.x;
    int eb = blockIdx.x, chunk = blockIdx.y;
    int e = eb * 256 + tid;
    int wbase = eb * 8, v0 = chunk * 256;
#pragma unroll
    for (int i = 0; i < 8; ++i)
        ch[i][tid] = maskT[(size_t)(wbase + i) * N + v0 + tid];
    int pos = 0;
    for (int c = 0; c < chunk; ++c) pos += cnt16[c * N + e];
    __syncthreads();
    int wl = tid >> 5;
    unsigned bit = 1u << (tid & 31);
    for (int v = 0; v < 256; ++v) {
        if (ch[wl][v] & bit) {
            if (pos < CAP) {
                size_t ofs = (size_t)(v0 + v) * N + e;
                elist[(size_t)e * CAP + pos] = v0 + v;
                eval_[(size_t)e * CAP + pos] = w1[ofs] * Hmat[ofs];
            }
            ++pos;
        }
    }
    if (chunk == 15) ecnt[e] = pos < CAP ? pos : CAP;
}

// ---------- dst[i,:] = (1/max(sum|val|,eps)) * sum val*src[list,:] ----------
__global__ __launch_bounds__(256) void spmm_k(const int* __restrict__ list,
                                              const float* __restrict__ val,
                                              const int* __restrict__ cnt,
                                              const float* __restrict__ src,
                                              float* __restrict__ dst) {
    int i = blockIdx.x;
    int f = threadIdx.x;
    int c = cnt[i];
    float ssum = 0.f;
    for (int t = 0; t < c; ++t) ssum += fabsf(val[(size_t)i * CAP + t]);
    float acc0 = 0.f, acc1 = 0.f;
    for (int t = 0; t < c; ++t) {
        int j = list[(size_t)i * CAP + t];
        float a = val[(size_t)i * CAP + t];
        acc0 += a * src[(size_t)j * OUT_FT + f];
        acc1 += a * src[(size_t)j * OUT_FT + f + 256];
    }
    float sc = 1.0f / fmaxf(ssum, EPSN);
    dst[(size_t)i * OUT_FT + f] = acc0 * sc;
    dst[(size_t)i * OUT_FT + f + 256] = acc1 * sc;
}

extern "C" void kernel_launch(void* const* d_in, const int* in_sizes, int n_in,
                              void* d_out, int out_size, void* d_ws, size_t ws_size,
                              hipStream_t stream) {
    const float* x      = (const float*)d_in[0];   // [4096,512]
    const float* Hmat   = (const float*)d_in[1];   // [4096,4096]
    const float* proj_w = (const float*)d_in[2];   // [512,512]
    const float* proj_b = (const float*)d_in[3];   // [512]
    const float* w1     = (const float*)d_in[4];   // [4096,4096]
    const float* w2     = (const float*)d_in[5];   // [4096,4096]
    float* out = (float*)d_out;

    char* ws = (char*)d_ws;
    float*    xn    = (float*)(ws + 0);           //  8 MB
    float*    cosm  = (float*)(ws + 8388608);     // 64 MB [8MB..72MB), dead after topk
    int*      elist = (int*)  (ws + 8388608);     //  4 MB (aliases dead cos)
    float*    eval_ = (float*)(ws + 12582912);    //  4 MB (aliases dead cos)
    float*    h     = (float*)(ws + 25165824);    //  8 MB (aliases dead cos)
    float*    h2    = (float*)(ws + 33554432);    //  8 MB (aliases dead cos)
    unsigned* maskT = (unsigned*)(ws + 75497472); //  2 MB (outside cos)
    int*      ecnt  = (int*)  (ws + 77594624);    // 16 KB
    int*      rcnt  = (int*)  (ws + 77611008);    // 16 KB
    int*      rlist = (int*)  (ws + 77660160);    //  4 MB (outside cos)
    float*    rval  = (float*)(ws + 81854464);    //  4 MB (outside cos)
    int*      cnt16 = (int*)  (ws + 86048768);    // 256 KB [16][4096]

    // 1. xn = x / max(||x||, eps)
    rownorm_k<<<N, 256, 0, stream>>>(x, xn);
    // 2. cos = xn @ xn^T: upper-tri blocks + exact mirror (bit-identical values)
    cos_sym_k<<<CNB * (CNB + 1) / 2, 256, 0, stream>>>(xn, cosm);
    mirror_k<<<CNB * (CNB - 1) / 2, 256, 0, stream>>>(cosm);
    // 3. topk/threshold -> maskT + row sparse lists
    topk_mask_k<<<N, 256, 0, stream>>>(cosm, maskT, w2, Hmat, rlist, rval, rcnt);
    // 4. h = x @ proj_w^T + proj_b   (cos region now dead; h aliases it)
    matmul_abt_k<<<dim3(OUT_FT / BN, N / BM), 256, 0, stream>>>(x, proj_w, proj_b, h,
                                                                IN_FT, IN_FT, IN_FT, OUT_FT);
    // 5. column lists: count -> fill at prefix offsets
    count_cols_k<<<dim3(16, 16), 256, 0, stream>>>(maskT, cnt16);
    fill_cols_k<<<dim3(16, 16), 256, 0, stream>>>(maskT, cnt16, w1, Hmat, elist, eval_, ecnt);
    // 6. h2[e,:] = normalize . gather-sum over column lists
    spmm_k<<<N, 256, 0, stream>>>(elist, eval_, ecnt, h, h2);
    // 7. out[v,:] = normalize . gather-sum over row lists
    spmm_k<<<N, 256, 0, stream>>>(rlist, rval, rcnt, h2, out);
}

// Round 8
// 381.132 us; speedup vs baseline: 4.6161x; 1.0297x over previous
//
#include <hip/hip_runtime.h>
#include <hip/hip_bf16.h>
#include <math.h>

#define N 4096
#define IN_FT 512
#define OUT_FT 512
#define COS_THR 0.5f
#define COS_K 10
#define EPSN 1e-12f
#define CAP 256          // max stored nnz per row/col (actual ~10)
#define NW (N / 32)      // bitmask words per row

#define BM 64
#define BN 64
#define BK 16

#define CB 128           // cos tile
#define CK 32            // cos k-step (barriers halved vs CK=16)
#define CNB (N / CB)     // 32 cos block-rows

// ---------- row-normalize x ----------
__global__ __launch_bounds__(256) void rownorm_k(const float* __restrict__ x,
                                                 float* __restrict__ xn) {
    int row = blockIdx.x;
    const float* xr = x + (size_t)row * IN_FT;
    float s = 0.f;
    for (int j = threadIdx.x; j < IN_FT; j += 256) { float v = xr[j]; s += v * v; }
    __shared__ float red[256];
    red[threadIdx.x] = s; __syncthreads();
    for (int off = 128; off > 0; off >>= 1) {
        if (threadIdx.x < off) red[threadIdx.x] += red[threadIdx.x + off];
        __syncthreads();
    }
    float inv = 1.0f / fmaxf(sqrtf(red[0]), 1e-12f);
    for (int j = threadIdx.x; j < IN_FT; j += 256)
        xn[(size_t)row * IN_FT + j] = xr[j] * inv;
}

// ---------- generic C = A @ B^T + bias (used for proj only) ----------
__global__ __launch_bounds__(256) void matmul_abt_k(const float* __restrict__ A,
                                                    const float* __restrict__ B,
                                                    const float* __restrict__ bias,
                                                    float* __restrict__ C,
                                                    int K, int lda, int ldb, int ldc) {
    __shared__ float As[BK][BM + 1];
    __shared__ float Bs[BK][BN + 1];
    int i0 = blockIdx.y * BM, j0 = blockIdx.x * BN;
    int tid = threadIdx.x;
    int tx = tid & 15, ty = tid >> 4;
    float acc[4][4] = {{0.f}};
    for (int k0 = 0; k0 < K; k0 += BK) {
#pragma unroll
        for (int l = 0; l < 4; ++l) {
            int idx = tid + l * 256;
            int m = idx >> 4, k = idx & 15;
            As[k][m] = A[(size_t)(i0 + m) * lda + k0 + k];
        }
#pragma unroll
        for (int l = 0; l < 4; ++l) {
            int idx = tid + l * 256;
            int n = idx >> 4, k = idx & 15;
            Bs[k][n] = B[(size_t)(j0 + n) * ldb + k0 + k];
        }
        __syncthreads();
#pragma unroll
        for (int k = 0; k < BK; ++k) {
            float a[4], b[4];
#pragma unroll
            for (int i = 0; i < 4; ++i) a[i] = As[k][ty * 4 + i];
#pragma unroll
            for (int j = 0; j < 4; ++j) b[j] = Bs[k][tx * 4 + j];
#pragma unroll
            for (int i = 0; i < 4; ++i)
#pragma unroll
                for (int j = 0; j < 4; ++j) acc[i][j] += a[i] * b[j];
        }
        __syncthreads();
    }
#pragma unroll
    for (int i = 0; i < 4; ++i) {
        int r = i0 + ty * 4 + i;
#pragma unroll
        for (int j = 0; j < 4; ++j) {
            int c = j0 + tx * 4 + j;
            float v = acc[i][j];
            if (bias) v += bias[c];
            C[(size_t)r * ldc + c] = v;
        }
    }
}

// ---------- symmetric cos GEMM: upper-tri blocks, mirror fused ----------
// Per-element chain = strict ascending k, one FMA per k (bit-identical to
// all prior rounds). Mirror store is exact: a*b==b*a bitwise in IEEE, so
// C[c][r] shares the bit pattern of C[r][c].
__global__ __launch_bounds__(256) void cos_sym_k(const float* __restrict__ A,
                                                 float* __restrict__ C) {
    __shared__ float As[CK][CB + 4];
    __shared__ float Bs[CK][CB + 4];
    int t = blockIdx.x;                       // 0 .. 527
    int by = 0;
    while (t >= CNB - by) { t -= CNB - by; ++by; }
    int bx = by + t;                          // by <= bx
    int i0 = by * CB, j0 = bx * CB;
    int tid = threadIdx.x;
    int tx = tid & 15, ty = tid >> 4;
    int sm = tid >> 1;                        // staging row 0..127
    int sk = (tid & 1) * 16;                  // staging k offset 0/16
    float acc[8][8] = {{0.f}};
    for (int k0 = 0; k0 < IN_FT; k0 += CK) {
        float4 a0 = *(const float4*)&A[(size_t)(i0 + sm) * IN_FT + k0 + sk + 0];
        float4 a1 = *(const float4*)&A[(size_t)(i0 + sm) * IN_FT + k0 + sk + 4];
        float4 a2 = *(const float4*)&A[(size_t)(i0 + sm) * IN_FT + k0 + sk + 8];
        float4 a3 = *(const float4*)&A[(size_t)(i0 + sm) * IN_FT + k0 + sk + 12];
        float4 b0 = *(const float4*)&A[(size_t)(j0 + sm) * IN_FT + k0 + sk + 0];
        float4 b1 = *(const float4*)&A[(size_t)(j0 + sm) * IN_FT + k0 + sk + 4];
        float4 b2 = *(const float4*)&A[(size_t)(j0 + sm) * IN_FT + k0 + sk + 8];
        float4 b3 = *(const float4*)&A[(size_t)(j0 + sm) * IN_FT + k0 + sk + 12];
        __syncthreads();                      // previous iter's LDS reads done
        As[sk + 0][sm] = a0.x;  As[sk + 1][sm] = a0.y;
        As[sk + 2][sm] = a0.z;  As[sk + 3][sm] = a0.w;
        As[sk + 4][sm] = a1.x;  As[sk + 5][sm] = a1.y;
        As[sk + 6][sm] = a1.z;  As[sk + 7][sm] = a1.w;
        As[sk + 8][sm] = a2.x;  As[sk + 9][sm] = a2.y;
        As[sk + 10][sm] = a2.z; As[sk + 11][sm] = a2.w;
        As[sk + 12][sm] = a3.x; As[sk + 13][sm] = a3.y;
        As[sk + 14][sm] = a3.z; As[sk + 15][sm] = a3.w;
        Bs[sk + 0][sm] = b0.x;  Bs[sk + 1][sm] = b0.y;
        Bs[sk + 2][sm] = b0.z;  Bs[sk + 3][sm] = b0.w;
        Bs[sk + 4][sm] = b1.x;  Bs[sk + 5][sm] = b1.y;
        Bs[sk + 6][sm] = b1.z;  Bs[sk + 7][sm] = b1.w;
        Bs[sk + 8][sm] = b2.x;  Bs[sk + 9][sm] = b2.y;
        Bs[sk + 10][sm] = b2.z; Bs[sk + 11][sm] = b2.w;
        Bs[sk + 12][sm] = b3.x; Bs[sk + 13][sm] = b3.y;
        Bs[sk + 14][sm] = b3.z; Bs[sk + 15][sm] = b3.w;
        __syncthreads();
#pragma unroll
        for (int k = 0; k < CK; ++k) {
            float a[8], b[8];
#pragma unroll
            for (int i = 0; i < 8; ++i) a[i] = As[k][ty * 8 + i];
#pragma unroll
            for (int j = 0; j < 8; ++j) b[j] = Bs[k][tx * 8 + j];
#pragma unroll
            for (int i = 0; i < 8; ++i)
#pragma unroll
                for (int j = 0; j < 8; ++j) acc[i][j] += a[i] * b[j];
        }
    }
    // upper block store (row-contiguous float4)
#pragma unroll
    for (int i = 0; i < 8; ++i) {
        int r = i0 + ty * 8 + i;
        float4 s0 = make_float4(acc[i][0], acc[i][1], acc[i][2], acc[i][3]);
        float4 s1 = make_float4(acc[i][4], acc[i][5], acc[i][6], acc[i][7]);
        *(float4*)&C[(size_t)r * N + j0 + tx * 8 + 0] = s0;
        *(float4*)&C[(size_t)r * N + j0 + tx * 8 + 4] = s1;
    }
    // mirrored block store (bit-identical values)
    if (bx != by) {
#pragma unroll
        for (int j = 0; j < 8; ++j) {
            int r = j0 + tx * 8 + j;
            float4 s0 = make_float4(acc[0][j], acc[1][j], acc[2][j], acc[3][j]);
            float4 s1 = make_float4(acc[4][j], acc[5][j], acc[6][j], acc[7][j]);
            *(float4*)&C[(size_t)r * N + i0 + ty * 8 + 0] = s0;
            *(float4*)&C[(size_t)r * N + i0 + ty * 8 + 4] = s1;
        }
    }
}

// ---------- per-row top-k + threshold -> transposed bitmask + row sparse list ----------
// Row lives in 16 regs/thread (slot c = element c*256+tid; ascending c ==
// ascending j). Per-pass comparisons and (value, index) tie-breaks are
// exactly the round-7 sequence -> selection bit-identical.
__global__ __launch_bounds__(256) void topk_mask_k(const float* __restrict__ cosm,
                                                   unsigned* __restrict__ maskT,
                                                   const float* __restrict__ w2,
                                                   const float* __restrict__ Hmat,
                                                   int* __restrict__ rlist,
                                                   float* __restrict__ rval,
                                                   int* __restrict__ rcnt) {
    int row = blockIdx.x;
    int tid = threadIdx.x;
    __shared__ unsigned char flag[N];
    __shared__ float wbv[4];
    __shared__ int wbi[4];
    __shared__ int wcnt[4];
    __shared__ int basev;
    int lane = tid & 63, wid = tid >> 6;
    const float* crow = cosm + (size_t)row * N;
    float v[16];
    unsigned fl = 0;
#pragma unroll
    for (int c = 0; c < 16; ++c) {
        v[c] = crow[c * 256 + tid];
        if (v[c] > COS_THR) fl |= 1u << c;
    }
    // --- iterative top-K ---
    for (int t = 0; t < COS_K; ++t) {
        float best = -INFINITY;
        int bidx = 0x7fffffff;
#pragma unroll
        for (int c = 0; c < 16; ++c) {
            if (v[c] > best) { best = v[c]; bidx = c * 256 + tid; }
        }
#pragma unroll
        for (int off = 32; off > 0; off >>= 1) {
            float v2 = __shfl_xor(best, off);
            int i2 = __shfl_xor(bidx, off);
            if (v2 > best || (v2 == best && i2 < bidx)) { best = v2; bidx = i2; }
        }
        __syncthreads();                       // wbv/wbi free for rewrite
        if (lane == 0) { wbv[wid] = best; wbi[wid] = bidx; }
        __syncthreads();
        float fb = wbv[0]; int fi = wbi[0];
#pragma unroll
        for (int w = 1; w < 4; ++w) {
            float v2 = wbv[w]; int i2 = wbi[w];
            if (v2 > fb || (v2 == fb && i2 < fi)) { fb = v2; fi = i2; }
        }
        if ((fi & 255) == tid) {               // owning thread invalidates + flags
            int s = fi >> 8;
            v[s] = -INFINITY;
            fl |= 1u << s;
        }
    }
    // --- spill flags to LDS for bitmask/ballot phases ---
#pragma unroll
    for (int c = 0; c < 16; ++c) flag[c * 256 + tid] = (fl >> c) & 1;
    __syncthreads();
    // --- transposed bitmask for the column build ---
    for (int wdx = tid; wdx < NW; wdx += 256) {
        unsigned bits = 0;
#pragma unroll
        for (int b = 0; b < 32; ++b) bits |= (flag[wdx * 32 + b] ? 1u : 0u) << b;
        maskT[(size_t)wdx * N + row] = bits;
    }
    // --- row sparse list via ballot compaction (deterministic e-ascending) ---
    if (tid == 0) basev = 0;
    __syncthreads();
    for (int c = 0; c < 16; ++c) {
        int j = c * 256 + tid;
        bool f = flag[j] != 0;
        unsigned long long b = __ballot(f);
        if (lane == 0) wcnt[wid] = __popcll(b);
        __syncthreads();
        int off = basev;
        for (int w = 0; w < wid; ++w) off += wcnt[w];
        int pos = off + __popcll(b & ((1ull << lane) - 1ull));
        if (f && pos < CAP) {
            size_t ofs = (size_t)row * N + j;
            rlist[(size_t)row * CAP + pos] = j;
            rval[(size_t)row * CAP + pos] = w2[ofs] * Hmat[ofs];
        }
        __syncthreads();
        if (tid == 0) basev += wcnt[0] + wcnt[1] + wcnt[2] + wcnt[3];
        __syncthreads();
    }
    if (tid == 0) rcnt[row] = basev < CAP ? basev : CAP;
}

// ---------- column build pass 1: per-(v-chunk, e) bit counts ----------
__global__ __launch_bounds__(256) void count_cols_k(const unsigned* __restrict__ maskT,
                                                    int* __restrict__ cnt16) {
    __shared__ unsigned ch[8][256];
    int tid = threadIdx.x;
    int eb = blockIdx.x, chunk = blockIdx.y;
    int wbase = eb * 8, v0 = chunk * 256;
#pragma unroll
    for (int i = 0; i < 8; ++i)
        ch[i][tid] = maskT[(size_t)(wbase + i) * N + v0 + tid];
    __syncthreads();
    int wl = tid >> 5, bp = tid & 31;
    int cnt = 0;
#pragma unroll 8
    for (int v = 0; v < 256; ++v) cnt += (ch[wl][v] >> bp) & 1;
    cnt16[chunk * N + eb * 256 + tid] = cnt;
}

// ---------- column build pass 2: fill at prefix offsets (deterministic) ----------
__global__ __launch_bounds__(256) void fill_cols_k(const unsigned* __restrict__ maskT,
                                                   const int* __restrict__ cnt16,
                                                   const float* __restrict__ w1,
                                                   const float* __restrict__ Hmat,
                                                   int* __restrict__ elist,
                                                   float* __restrict__ eval_,
                                                   int* __restrict__ ecnt) {
    __shared__ unsigned ch[8][256];
    int tid = threadIdx.x;
    int eb = blockIdx.x, chunk = blockIdx.y;
    int e = eb * 256 + tid;
    int wbase = eb * 8, v0 = chunk * 256;
#pragma unroll
    for (int i = 0; i < 8; ++i)
        ch[i][tid] = maskT[(size_t)(wbase + i) * N + v0 + tid];
    int pos = 0;
    for (int c = 0; c < chunk; ++c) pos += cnt16[c * N + e];
    __syncthreads();
    int wl = tid >> 5;
    unsigned bit = 1u << (tid & 31);
    for (int v = 0; v < 256; ++v) {
        if (ch[wl][v] & bit) {
            if (pos < CAP) {
                size_t ofs = (size_t)(v0 + v) * N + e;
                elist[(size_t)e * CAP + pos] = v0 + v;
                eval_[(size_t)e * CAP + pos] = w1[ofs] * Hmat[ofs];
            }
            ++pos;
        }
    }
    if (chunk == 15) ecnt[e] = pos < CAP ? pos : CAP;
}

// ---------- dst[i,:] = (1/max(sum|val|,eps)) * sum val*src[list,:] ----------
__global__ __launch_bounds__(256) void spmm_k(const int* __restrict__ list,
                                              const float* __restrict__ val,
                                              const int* __restrict__ cnt,
                                              const float* __restrict__ src,
                                              float* __restrict__ dst) {
    int i = blockIdx.x;
    int f = threadIdx.x;
    int c = cnt[i];
    float ssum = 0.f;
    for (int t = 0; t < c; ++t) ssum += fabsf(val[(size_t)i * CAP + t]);
    float acc0 = 0.f, acc1 = 0.f;
    for (int t = 0; t < c; ++t) {
        int j = list[(size_t)i * CAP + t];
        float a = val[(size_t)i * CAP + t];
        acc0 += a * src[(size_t)j * OUT_FT + f];
        acc1 += a * src[(size_t)j * OUT_FT + f + 256];
    }
    float sc = 1.0f / fmaxf(ssum, EPSN);
    dst[(size_t)i * OUT_FT + f] = acc0 * sc;
    dst[(size_t)i * OUT_FT + f + 256] = acc1 * sc;
}

extern "C" void kernel_launch(void* const* d_in, const int* in_sizes, int n_in,
                              void* d_out, int out_size, void* d_ws, size_t ws_size,
                              hipStream_t stream) {
    const float* x      = (const float*)d_in[0];   // [4096,512]
    const float* Hmat   = (const float*)d_in[1];   // [4096,4096]
    const float* proj_w = (const float*)d_in[2];   // [512,512]
    const float* proj_b = (const float*)d_in[3];   // [512]
    const float* w1     = (const float*)d_in[4];   // [4096,4096]
    const float* w2     = (const float*)d_in[5];   // [4096,4096]
    float* out = (float*)d_out;

    char* ws = (char*)d_ws;
    float*    xn    = (float*)(ws + 0);           //  8 MB
    float*    cosm  = (float*)(ws + 8388608);     // 64 MB [8MB..72MB), dead after topk
    int*      elist = (int*)  (ws + 8388608);     //  4 MB (aliases dead cos)
    float*    eval_ = (float*)(ws + 12582912);    //  4 MB (aliases dead cos)
    float*    h     = (float*)(ws + 25165824);    //  8 MB (aliases dead cos)
    float*    h2    = (float*)(ws + 33554432);    //  8 MB (aliases dead cos)
    unsigned* maskT = (unsigned*)(ws + 75497472); //  2 MB (outside cos)
    int*      ecnt  = (int*)  (ws + 77594624);    // 16 KB
    int*      rcnt  = (int*)  (ws + 77611008);    // 16 KB
    int*      rlist = (int*)  (ws + 77660160);    //  4 MB (outside cos)
    float*    rval  = (float*)(ws + 81854464);    //  4 MB (outside cos)
    int*      cnt16 = (int*)  (ws + 86048768);    // 256 KB [16][4096]

    // 1. xn = x / max(||x||, eps)
    rownorm_k<<<N, 256, 0, stream>>>(x, xn);
    // 2. cos = xn @ xn^T: upper-tri blocks, mirror fused (bit-identical values)
    cos_sym_k<<<CNB * (CNB + 1) / 2, 256, 0, stream>>>(xn, cosm);
    // 3. topk/threshold -> maskT + row sparse lists (register-resident rows)
    topk_mask_k<<<N, 256, 0, stream>>>(cosm, maskT, w2, Hmat, rlist, rval, rcnt);
    // 4. h = x @ proj_w^T + proj_b   (cos region now dead; h aliases it)
    matmul_abt_k<<<dim3(OUT_FT / BN, N / BM), 256, 0, stream>>>(x, proj_w, proj_b, h,
                                                                IN_FT, IN_FT, IN_FT, OUT_FT);
    // 5. column lists: count -> fill at prefix offsets
    count_cols_k<<<dim3(16, 16), 256, 0, stream>>>(maskT, cnt16);
    fill_cols_k<<<dim3(16, 16), 256, 0, stream>>>(maskT, cnt16, w1, Hmat, elist, eval_, ecnt);
    // 6. h2[e,:] = normalize . gather-sum over column lists
    spmm_k<<<N, 256, 0, stream>>>(elist, eval_, ecnt, h, h2);
    // 7. out[v,:] = normalize . gather-sum over row lists
    spmm_k<<<N, 256, 0, stream>>>(rlist, rval, rcnt, h2, out);
}

// Round 9
// 369.049 us; speedup vs baseline: 4.7672x; 1.0327x over previous
//
#include <hip/hip_runtime.h>
#include <hip/hip_bf16.h>
#include <math.h>

#define N 4096
#define IN_FT 512
#define OUT_FT 512
#define COS_THR 0.5f
#define COS_K 10
#define EPSN 1e-12f
#define CAP 256          // max stored nnz per row/col (actual ~10)
#define NW (N / 32)      // bitmask words per row

#define CB 128           // cos tile
#define CK 32            // cos k-step
#define CNB (N / CB)     // 32 cos block-rows

typedef short s16x8 __attribute__((ext_vector_type(8)));
typedef float f32x4 __attribute__((ext_vector_type(4)));

__device__ __forceinline__ unsigned short f2bf(float f) {
    unsigned u = __float_as_uint(f);
    u += 0x7fff + ((u >> 16) & 1);          // RNE to bf16
    return (unsigned short)(u >> 16);
}
__device__ __forceinline__ float bf2f(unsigned short h) {
    return __uint_as_float(((unsigned)h) << 16);
}

// ---------- row-normalize x ----------
__global__ __launch_bounds__(256) void rownorm_k(const float* __restrict__ x,
                                                 float* __restrict__ xn) {
    int row = blockIdx.x;
    const float* xr = x + (size_t)row * IN_FT;
    float s = 0.f;
    for (int j = threadIdx.x; j < IN_FT; j += 256) { float v = xr[j]; s += v * v; }
    __shared__ float red[256];
    red[threadIdx.x] = s; __syncthreads();
    for (int off = 128; off > 0; off >>= 1) {
        if (threadIdx.x < off) red[threadIdx.x] += red[threadIdx.x + off];
        __syncthreads();
    }
    float inv = 1.0f / fmaxf(sqrtf(red[0]), 1e-12f);
    for (int j = threadIdx.x; j < IN_FT; j += 256)
        xn[(size_t)row * IN_FT + j] = xr[j] * inv;
}

// ---------- symmetric cos GEMM: upper-tri blocks, mirror fused ----------
// LDS uses a float4-chunk permutation perm(ci)=(ci>>1)|((ci&1)<<4) so the
// per-lane b-fragment reads are contiguous 256B spans (2-way, free) instead
// of 32B-strided (4-way conflict). Pure physical relocation: the a[i]/b[j]
// VALUES and the ascending-k FMA chain are bit-identical to rounds 0-8.
__global__ __launch_bounds__(256) void cos_sym_k(const float* __restrict__ A,
                                                 float* __restrict__ C) {
    __shared__ __align__(16) float As[CK][CB + 4];
    __shared__ __align__(16) float Bs[CK][CB + 4];
    int t = blockIdx.x;                       // 0 .. 527
    int by = 0;
    while (t >= CNB - by) { t -= CNB - by; ++by; }
    int bx = by + t;                          // by <= bx
    int i0 = by * CB, j0 = bx * CB;
    int tid = threadIdx.x;
    int tx = tid & 15, ty = tid >> 4;
    int sm = tid >> 1;                        // staging row 0..127
    int sk = (tid & 1) * 16;                  // staging k offset 0/16
    // permuted physical column for staging writes of logical col sm
    int sch = sm >> 2;
    int pcol = (((sch >> 1) | ((sch & 1) << 4)) << 2) | (sm & 3);
    float acc[8][8] = {{0.f}};
    for (int k0 = 0; k0 < IN_FT; k0 += CK) {
        float4 a0 = *(const float4*)&A[(size_t)(i0 + sm) * IN_FT + k0 + sk + 0];
        float4 a1 = *(const float4*)&A[(size_t)(i0 + sm) * IN_FT + k0 + sk + 4];
        float4 a2 = *(const float4*)&A[(size_t)(i0 + sm) * IN_FT + k0 + sk + 8];
        float4 a3 = *(const float4*)&A[(size_t)(i0 + sm) * IN_FT + k0 + sk + 12];
        float4 b0 = *(const float4*)&A[(size_t)(j0 + sm) * IN_FT + k0 + sk + 0];
        float4 b1 = *(const float4*)&A[(size_t)(j0 + sm) * IN_FT + k0 + sk + 4];
        float4 b2 = *(const float4*)&A[(size_t)(j0 + sm) * IN_FT + k0 + sk + 8];
        float4 b3 = *(const float4*)&A[(size_t)(j0 + sm) * IN_FT + k0 + sk + 12];
        __syncthreads();                      // previous iter's LDS reads done
        As[sk + 0][pcol] = a0.x;  As[sk + 1][pcol] = a0.y;
        As[sk + 2][pcol] = a0.z;  As[sk + 3][pcol] = a0.w;
        As[sk + 4][pcol] = a1.x;  As[sk + 5][pcol] = a1.y;
        As[sk + 6][pcol] = a1.z;  As[sk + 7][pcol] = a1.w;
        As[sk + 8][pcol] = a2.x;  As[sk + 9][pcol] = a2.y;
        As[sk + 10][pcol] = a2.z; As[sk + 11][pcol] = a2.w;
        As[sk + 12][pcol] = a3.x; As[sk + 13][pcol] = a3.y;
        As[sk + 14][pcol] = a3.z; As[sk + 15][pcol] = a3.w;
        Bs[sk + 0][pcol] = b0.x;  Bs[sk + 1][pcol] = b0.y;
        Bs[sk + 2][pcol] = b0.z;  Bs[sk + 3][pcol] = b0.w;
        Bs[sk + 4][pcol] = b1.x;  Bs[sk + 5][pcol] = b1.y;
        Bs[sk + 6][pcol] = b1.z;  Bs[sk + 7][pcol] = b1.w;
        Bs[sk + 8][pcol] = b2.x;  Bs[sk + 9][pcol] = b2.y;
        Bs[sk + 10][pcol] = b2.z; Bs[sk + 11][pcol] = b2.w;
        Bs[sk + 12][pcol] = b3.x; Bs[sk + 13][pcol] = b3.y;
        Bs[sk + 14][pcol] = b3.z; Bs[sk + 15][pcol] = b3.w;
        __syncthreads();
#pragma unroll
        for (int k = 0; k < CK; ++k) {
            // logical cols 8*ty..8*ty+7 live at phys float4s [4*ty] and [64+4*ty]
            float4 af0 = *(const float4*)&As[k][4 * ty];
            float4 af1 = *(const float4*)&As[k][64 + 4 * ty];
            float4 bg0 = *(const float4*)&Bs[k][4 * tx];
            float4 bg1 = *(const float4*)&Bs[k][64 + 4 * tx];
            float a[8] = {af0.x, af0.y, af0.z, af0.w, af1.x, af1.y, af1.z, af1.w};
            float b[8] = {bg0.x, bg0.y, bg0.z, bg0.w, bg1.x, bg1.y, bg1.z, bg1.w};
#pragma unroll
            for (int i = 0; i < 8; ++i)
#pragma unroll
                for (int j = 0; j < 8; ++j) acc[i][j] += a[i] * b[j];
        }
    }
    // upper block store (row-contiguous float4)
#pragma unroll
    for (int i = 0; i < 8; ++i) {
        int r = i0 + ty * 8 + i;
        float4 s0 = make_float4(acc[i][0], acc[i][1], acc[i][2], acc[i][3]);
        float4 s1 = make_float4(acc[i][4], acc[i][5], acc[i][6], acc[i][7]);
        *(float4*)&C[(size_t)r * N + j0 + tx * 8 + 0] = s0;
        *(float4*)&C[(size_t)r * N + j0 + tx * 8 + 4] = s1;
    }
    // mirrored block store (bit-identical values: IEEE a*b == b*a)
    if (bx != by) {
#pragma unroll
        for (int j = 0; j < 8; ++j) {
            int r = j0 + tx * 8 + j;
            float4 s0 = make_float4(acc[0][j], acc[1][j], acc[2][j], acc[3][j]);
            float4 s1 = make_float4(acc[4][j], acc[5][j], acc[6][j], acc[7][j]);
            *(float4*)&C[(size_t)r * N + i0 + ty * 8 + 0] = s0;
            *(float4*)&C[(size_t)r * N + i0 + ty * 8 + 4] = s1;
        }
    }
}

// ---------- per-row top-k + threshold -> transposed bitmask + row sparse list ----------
// Thread owns contiguous j = tid*16..tid*16+15 (float4 loads). Per-thread
// ascending scan keeps lowest-j on ties; cross-lane comparator uses global
// (value, j) -> selected SET identical to all prior rounds.
__global__ __launch_bounds__(256) void topk_mask_k(const float* __restrict__ cosm,
                                                   unsigned* __restrict__ maskT,
                                                   const float* __restrict__ w2,
                                                   const float* __restrict__ Hmat,
                                                   int* __restrict__ rlist,
                                                   float* __restrict__ rval,
                                                   int* __restrict__ rcnt) {
    int row = blockIdx.x;
    int tid = threadIdx.x;
    __shared__ unsigned char flag[N];
    __shared__ float wbv[4];
    __shared__ int wbi[4];
    __shared__ int wcnt[4];
    __shared__ int basev;
    int lane = tid & 63, wid = tid >> 6;
    const float* crow = cosm + (size_t)row * N;
    float v[16];
    unsigned fl = 0;
#pragma unroll
    for (int q = 0; q < 4; ++q) {
        float4 f4 = *(const float4*)&crow[tid * 16 + q * 4];
        v[q * 4 + 0] = f4.x; v[q * 4 + 1] = f4.y;
        v[q * 4 + 2] = f4.z; v[q * 4 + 3] = f4.w;
    }
#pragma unroll
    for (int c = 0; c < 16; ++c)
        if (v[c] > COS_THR) fl |= 1u << c;
    // --- iterative top-K ---
    for (int t = 0; t < COS_K; ++t) {
        float best = -INFINITY;
        int bidx = 0x7fffffff;
#pragma unroll
        for (int c = 0; c < 16; ++c)
            if (v[c] > best) { best = v[c]; bidx = tid * 16 + c; }
#pragma unroll
        for (int off = 32; off > 0; off >>= 1) {
            float v2 = __shfl_xor(best, off);
            int i2 = __shfl_xor(bidx, off);
            if (v2 > best || (v2 == best && i2 < bidx)) { best = v2; bidx = i2; }
        }
        __syncthreads();
        if (lane == 0) { wbv[wid] = best; wbi[wid] = bidx; }
        __syncthreads();
        float fb = wbv[0]; int fi = wbi[0];
#pragma unroll
        for (int w = 1; w < 4; ++w) {
            float v2 = wbv[w]; int i2 = wbi[w];
            if (v2 > fb || (v2 == fb && i2 < fi)) { fb = v2; fi = i2; }
        }
        if ((fi >> 4) == tid) {                // owning thread invalidates + flags
            v[fi & 15] = -INFINITY;
            fl |= 1u << (fi & 15);
        }
    }
    // --- spill flags to LDS ---
#pragma unroll
    for (int c = 0; c < 16; ++c) flag[tid * 16 + c] = (fl >> c) & 1;
    __syncthreads();
    // --- transposed bitmask for the column build ---
    for (int wdx = tid; wdx < NW; wdx += 256) {
        unsigned bits = 0;
#pragma unroll
        for (int b = 0; b < 32; ++b) bits |= (flag[wdx * 32 + b] ? 1u : 0u) << b;
        maskT[(size_t)wdx * N + row] = bits;
    }
    // --- row sparse list via ballot compaction (deterministic e-ascending) ---
    if (tid == 0) basev = 0;
    __syncthreads();
    for (int c = 0; c < 16; ++c) {
        int j = c * 256 + tid;
        bool f = flag[j] != 0;
        unsigned long long b = __ballot(f);
        if (lane == 0) wcnt[wid] = __popcll(b);
        __syncthreads();
        int off = basev;
        for (int w = 0; w < wid; ++w) off += wcnt[w];
        int pos = off + __popcll(b & ((1ull << lane) - 1ull));
        if (f && pos < CAP) {
            size_t ofs = (size_t)row * N + j;
            rlist[(size_t)row * CAP + pos] = j;
            rval[(size_t)row * CAP + pos] = w2[ofs] * Hmat[ofs];
        }
        __syncthreads();
        if (tid == 0) basev += wcnt[0] + wcnt[1] + wcnt[2] + wcnt[3];
        __syncthreads();
    }
    if (tid == 0) rcnt[row] = basev < CAP ? basev : CAP;
}

// ---------- split x and proj_w into bf16 (hi, lo) pairs ----------
__global__ __launch_bounds__(256) void cast_split_k(const float* __restrict__ x,
                                                    const float* __restrict__ w,
                                                    unsigned short* __restrict__ xh,
                                                    unsigned short* __restrict__ xl,
                                                    unsigned short* __restrict__ wh,
                                                    unsigned short* __restrict__ wl) {
    const int totx = (N * IN_FT) / 4;          // 524288 float4s
    int idx = blockIdx.x * 256 + threadIdx.x;  // grid sized exactly
    bool isx = idx < totx;
    int i4 = isx ? idx : idx - totx;
    float4 f = isx ? ((const float4*)x)[i4] : ((const float4*)w)[i4];
    ushort4 hi, lo;
    hi.x = f2bf(f.x); lo.x = f2bf(f.x - bf2f(hi.x));
    hi.y = f2bf(f.y); lo.y = f2bf(f.y - bf2f(hi.y));
    hi.z = f2bf(f.z); lo.z = f2bf(f.z - bf2f(hi.z));
    hi.w = f2bf(f.w); lo.w = f2bf(f.w - bf2f(hi.w));
    if (isx) { ((ushort4*)xh)[i4] = hi; ((ushort4*)xl)[i4] = lo; }
    else     { ((ushort4*)wh)[i4] = hi; ((ushort4*)wl)[i4] = lo; }
}

// ---------- h = x @ proj_w^T + b via bf16x3 MFMA (err ~1e-5; not a selection path) ----------
// frag layout (guide/m89): A/B lane l reads 8 contiguous bf16 at row (l&15),
// k-offset 8*(l>>4); D: col = l&15, row = (l>>4)*4 + reg.
__global__ __launch_bounds__(256) void proj_mfma_k(const unsigned short* __restrict__ xh,
                                                   const unsigned short* __restrict__ xl,
                                                   const unsigned short* __restrict__ wh,
                                                   const unsigned short* __restrict__ wl,
                                                   const float* __restrict__ bias,
                                                   float* __restrict__ h) {
    int tid = threadIdx.x;
    int wave = tid >> 6, l = tid & 63;
    int m0 = blockIdx.y * 64 + wave * 16;
    int n0 = blockIdx.x * 64;
    int lr = l & 15;
    int kq = (l >> 4) * 8;
    const unsigned short* pah = xh + (size_t)(m0 + lr) * IN_FT + kq;
    const unsigned short* pal = xl + (size_t)(m0 + lr) * IN_FT + kq;
    f32x4 acc[4] = {};
    for (int k0 = 0; k0 < IN_FT; k0 += 32) {
        s16x8 ah = *(const s16x8*)(pah + k0);
        s16x8 al = *(const s16x8*)(pal + k0);
#pragma unroll
        for (int g = 0; g < 4; ++g) {
            const unsigned short* pbh = wh + (size_t)(n0 + g * 16 + lr) * IN_FT + kq + k0;
            const unsigned short* pbl = wl + (size_t)(n0 + g * 16 + lr) * IN_FT + kq + k0;
            s16x8 bh = *(const s16x8*)pbh;
            s16x8 bl = *(const s16x8*)pbl;
            acc[g] = __builtin_amdgcn_mfma_f32_16x16x32_bf16(ah, bh, acc[g], 0, 0, 0);
            acc[g] = __builtin_amdgcn_mfma_f32_16x16x32_bf16(ah, bl, acc[g], 0, 0, 0);
            acc[g] = __builtin_amdgcn_mfma_f32_16x16x32_bf16(al, bh, acc[g], 0, 0, 0);
        }
    }
#pragma unroll
    for (int g = 0; g < 4; ++g) {
#pragma unroll
        for (int r = 0; r < 4; ++r) {
            int m = m0 + (l >> 4) * 4 + r;
            int n = n0 + g * 16 + lr;
            h[(size_t)m * OUT_FT + n] = acc[g][r] + bias[n];
        }
    }
}

// ---------- column build pass 1: per-(v-chunk, e) bit counts ----------
__global__ __launch_bounds__(256) void count_cols_k(const unsigned* __restrict__ maskT,
                                                    int* __restrict__ cnt16) {
    __shared__ unsigned ch[8][256];
    int tid = threadIdx.x;
    int eb = blockIdx.x, chunk = blockIdx.y;
    int wbase = eb * 8, v0 = chunk * 256;
#pragma unroll
    for (int i = 0; i < 8; ++i)
        ch[i][tid] = maskT[(size_t)(wbase + i) * N + v0 + tid];
    __syncthreads();
    int wl = tid >> 5, bp = tid & 31;
    int cnt = 0;
#pragma unroll 8
    for (int v = 0; v < 256; ++v) cnt += (ch[wl][v] >> bp) & 1;
    cnt16[chunk * N + eb * 256 + tid] = cnt;
}

// ---------- column build pass 2: fill at prefix offsets (deterministic) ----------
__global__ __launch_bounds__(256) void fill_cols_k(const unsigned* __restrict__ maskT,
                                                   const int* __restrict__ cnt16,
                                                   const float* __restrict__ w1,
                                                   const float* __restrict__ Hmat,
                                                   int* __restrict__ elist,
                                                   float* __restrict__ eval_,
                                                   int* __restrict__ ecnt) {
    __shared__ unsigned ch[8][256];
    int tid = threadIdx.x;
    int eb = blockIdx.x, chunk = blockIdx.y;
    int e = eb * 256 + tid;
    int wbase = eb * 8, v0 = chunk * 256;
#pragma unroll
    for (int i = 0; i < 8; ++i)
        ch[i][tid] = maskT[(size_t)(wbase + i) * N + v0 + tid];
    int pos = 0;
    for (int c = 0; c < chunk; ++c) pos += cnt16[c * N + e];
    __syncthreads();
    int wl = tid >> 5;
    unsigned bit = 1u << (tid & 31);
    for (int v = 0; v < 256; ++v) {
        if (ch[wl][v] & bit) {
            if (pos < CAP) {
                size_t ofs = (size_t)(v0 + v) * N + e;
                elist[(size_t)e * CAP + pos] = v0 + v;
                eval_[(size_t)e * CAP + pos] = w1[ofs] * Hmat[ofs];
            }
            ++pos;
        }
    }
    if (chunk == 15) ecnt[e] = pos < CAP ? pos : CAP;
}

// ---------- dst[i,:] = (1/max(sum|val|,eps)) * sum val*src[list,:] ----------
__global__ __launch_bounds__(256) void spmm_k(const int* __restrict__ list,
                                              const float* __restrict__ val,
                                              const int* __restrict__ cnt,
                                              const float* __restrict__ src,
                                              float* __restrict__ dst) {
    int i = blockIdx.x;
    int f2 = threadIdx.x;                      // float2 index 0..255
    int c = cnt[i];
    float ssum = 0.f;
    for (int t = 0; t < c; ++t) ssum += fabsf(val[(size_t)i * CAP + t]);
    float acc0 = 0.f, acc1 = 0.f;
    for (int t = 0; t < c; ++t) {
        int j = list[(size_t)i * CAP + t];
        float a = val[(size_t)i * CAP + t];
        float2 s = *(const float2*)&src[(size_t)j * OUT_FT + f2 * 2];
        acc0 += a * s.x;
        acc1 += a * s.y;
    }
    float sc = 1.0f / fmaxf(ssum, EPSN);
    float2 o = make_float2(acc0 * sc, acc1 * sc);
    *(float2*)&dst[(size_t)i * OUT_FT + f2 * 2] = o;
}

extern "C" void kernel_launch(void* const* d_in, const int* in_sizes, int n_in,
                              void* d_out, int out_size, void* d_ws, size_t ws_size,
                              hipStream_t stream) {
    const float* x      = (const float*)d_in[0];   // [4096,512]
    const float* Hmat   = (const float*)d_in[1];   // [4096,4096]
    const float* proj_w = (const float*)d_in[2];   // [512,512]
    const float* proj_b = (const float*)d_in[3];   // [512]
    const float* w1     = (const float*)d_in[4];   // [4096,4096]
    const float* w2     = (const float*)d_in[5];   // [4096,4096]
    float* out = (float*)d_out;

    char* ws = (char*)d_ws;
    float*          xn    = (float*)(ws + 0);           //  8 MB
    float*          cosm  = (float*)(ws + 8388608);     // 64 MB [8MB..72MB), dead after topk
    int*            elist = (int*)  (ws + 8388608);     //  4 MB (aliases dead cos)
    float*          eval_ = (float*)(ws + 12582912);    //  4 MB (aliases dead cos)
    float*          h     = (float*)(ws + 25165824);    //  8 MB (aliases dead cos)
    float*          h2    = (float*)(ws + 33554432);    //  8 MB (aliases dead cos)
    unsigned short* xhi   = (unsigned short*)(ws + 41943040);  // 4 MB (aliases dead cos)
    unsigned short* xlo   = (unsigned short*)(ws + 46137344);  // 4 MB (aliases dead cos)
    unsigned short* whi   = (unsigned short*)(ws + 50331648);  // 512 KB (aliases dead cos)
    unsigned short* wlo   = (unsigned short*)(ws + 50855936);  // 512 KB (aliases dead cos)
    unsigned*       maskT = (unsigned*)(ws + 75497472); //  2 MB (outside cos)
    int*            ecnt  = (int*)  (ws + 77594624);    // 16 KB
    int*            rcnt  = (int*)  (ws + 77611008);    // 16 KB
    int*            rlist = (int*)  (ws + 77660160);    //  4 MB (outside cos)
    float*          rval  = (float*)(ws + 81854464);    //  4 MB (outside cos)
    int*            cnt16 = (int*)  (ws + 86048768);    // 256 KB [16][4096]

    // 1. xn = x / max(||x||, eps)
    rownorm_k<<<N, 256, 0, stream>>>(x, xn);
    // 2. cos = xn @ xn^T: upper-tri blocks, mirror fused (bit-identical values)
    cos_sym_k<<<CNB * (CNB + 1) / 2, 256, 0, stream>>>(xn, cosm);
    // 3. topk/threshold -> maskT + row sparse lists (selection-identical)
    topk_mask_k<<<N, 256, 0, stream>>>(cosm, maskT, w2, Hmat, rlist, rval, rcnt);
    // 4. h = x @ proj_w^T + proj_b  (bf16x3 MFMA; buffers alias dead cos)
    cast_split_k<<<(N * IN_FT + OUT_FT * IN_FT) / 1024, 256, 0, stream>>>(
        x, proj_w, xhi, xlo, whi, wlo);
    proj_mfma_k<<<dim3(OUT_FT / 64, N / 64), 256, 0, stream>>>(xhi, xlo, whi, wlo, proj_b, h);
    // 5. column lists: count -> fill at prefix offsets
    count_cols_k<<<dim3(16, 16), 256, 0, stream>>>(maskT, cnt16);
    fill_cols_k<<<dim3(16, 16), 256, 0, stream>>>(maskT, cnt16, w1, Hmat, elist, eval_, ecnt);
    // 6. h2[e,:] = normalize . gather-sum over column lists
    spmm_k<<<N, 256, 0, stream>>>(elist, eval_, ecnt, h, h2);
    // 7. out[v,:] = normalize . gather-sum over row lists
    spmm_k<<<N, 256, 0, stream>>>(rlist, rval, rcnt, h2, out);
}